// Round 1
// baseline (610.248 us; speedup 1.0000x reference)
//
#include <hip/hip_runtime.h>
#include <math.h>

// Problem constants
#define DMODEL 768
#define SEQ    2048
#define BATCH  2
#define NHEAD  12
#define DKH    64
#define NROWS  (BATCH*SEQ)        /* 4096 */
#define PER_BATCH (SEQ*DMODEL)    /* 1572864 */
#define PER_HEAD  (SEQ*DKH)       /* 131072 */
#define ATT_SCALE 0.125f

// ---------------------------------------------------------------------------
// Generic fp32 GEMM:  C = A @ W^T + bias
// A: 4096 x 768 row-major, W: 768 x 768 row-major (torch Linear layout), C: 4096 x 768
// 128x128 tile, BK=32, 256 threads, 8x8 micro-tile per thread.
// blockIdx.z selects one of three (W, bias, C) sets so QKV fuses into one launch.
// ---------------------------------------------------------------------------
__global__ __launch_bounds__(256, 1) void gemm128(
    const float* __restrict__ A,
    const float* __restrict__ W0, const float* __restrict__ W1, const float* __restrict__ W2,
    const float* __restrict__ b0, const float* __restrict__ b1, const float* __restrict__ b2,
    float* __restrict__ C0, float* __restrict__ C1, float* __restrict__ C2)
{
    constexpr int K = 768, N = 768;
    const float* W; const float* bias; float* C;
    if (blockIdx.z == 0)      { W = W0; bias = b0; C = C0; }
    else if (blockIdx.z == 1) { W = W1; bias = b1; C = C1; }
    else                      { W = W2; bias = b2; C = C2; }

    const int mBase = blockIdx.x * 128;
    const int nBase = blockIdx.y * 128;

    // Transposed-in-LDS tiles; leading pad 132 keeps writes 2-way (free) and
    // compute-phase float4 reads 16B-aligned + conflict-free.
    __shared__ __align__(16) float As[32][132];
    __shared__ __align__(16) float Bs[32][132];

    const int tid = threadIdx.x;
    const int tx  = tid & 15;    // n direction
    const int ty  = tid >> 4;    // m direction

    float acc[8][8];
    #pragma unroll
    for (int i = 0; i < 8; ++i)
        #pragma unroll
        for (int j = 0; j < 8; ++j) acc[i][j] = 0.f;

    for (int kb = 0; kb < K; kb += 32) {
        #pragma unroll
        for (int r = 0; r < 4; ++r) {
            int idx = tid + 256 * r;      // 0..1023
            int row = idx >> 3;           // 0..127
            int c4  = idx & 7;            // 0..7
            float4 av = *(const float4*)&A[(size_t)(mBase + row) * K + kb + c4 * 4];
            As[c4*4+0][row] = av.x; As[c4*4+1][row] = av.y;
            As[c4*4+2][row] = av.z; As[c4*4+3][row] = av.w;
            float4 wv = *(const float4*)&W[(size_t)(nBase + row) * K + kb + c4 * 4];
            Bs[c4*4+0][row] = wv.x; Bs[c4*4+1][row] = wv.y;
            Bs[c4*4+2][row] = wv.z; Bs[c4*4+3][row] = wv.w;
        }
        __syncthreads();
        #pragma unroll
        for (int kk = 0; kk < 32; ++kk) {
            float4 a0 = *(const float4*)&As[kk][ty * 8];
            float4 a1 = *(const float4*)&As[kk][ty * 8 + 4];
            float4 w0 = *(const float4*)&Bs[kk][tx * 8];
            float4 w1 = *(const float4*)&Bs[kk][tx * 8 + 4];
            float a[8] = {a0.x, a0.y, a0.z, a0.w, a1.x, a1.y, a1.z, a1.w};
            float b[8] = {w0.x, w0.y, w0.z, w0.w, w1.x, w1.y, w1.z, w1.w};
            #pragma unroll
            for (int i = 0; i < 8; ++i)
                #pragma unroll
                for (int j = 0; j < 8; ++j)
                    acc[i][j] += a[i] * b[j];
        }
        __syncthreads();
    }

    float bv[8];
    #pragma unroll
    for (int j = 0; j < 8; ++j) bv[j] = bias[nBase + tx * 8 + j];

    #pragma unroll
    for (int i = 0; i < 8; ++i) {
        int row = mBase + ty * 8 + i;
        float* Crow = C + (size_t)row * N + nBase + tx * 8;
        float4 o0, o1;
        o0.x = acc[i][0] + bv[0]; o0.y = acc[i][1] + bv[1];
        o0.z = acc[i][2] + bv[2]; o0.w = acc[i][3] + bv[3];
        o1.x = acc[i][4] + bv[4]; o1.y = acc[i][5] + bv[5];
        o1.z = acc[i][6] + bv[6]; o1.w = acc[i][7] + bv[7];
        *(float4*)&Crow[0] = o0;
        *(float4*)&Crow[4] = o1;
    }
}

// ---------------------------------------------------------------------------
// Phase A: per (b,h) pair, partial M = K_h^T V_h over a 256-row t-chunk.
// grid (8 chunks, 24 pairs). Output Mpart[pair][chunk][64][64].
// ---------------------------------------------------------------------------
__global__ __launch_bounds__(256, 1) void kv_outer(
    const float* __restrict__ Kbuf, const float* __restrict__ Vbuf,
    float* __restrict__ Mpart)
{
    const int chunk = blockIdx.x;   // 0..7
    const int p     = blockIdx.y;   // 0..23  (b*12 + h)
    const int b = p / NHEAD, h = p % NHEAD;
    const float* Kb = Kbuf + (size_t)b * PER_BATCH + (size_t)h * PER_HEAD + (size_t)chunk * 256 * DKH;
    const float* Vb = Vbuf + (size_t)b * PER_BATCH + (size_t)h * PER_HEAD + (size_t)chunk * 256 * DKH;

    __shared__ __align__(16) float Ks[32][64];
    __shared__ __align__(16) float Vs[32][64];

    const int tid = threadIdx.x;
    const int tx  = tid & 15;    // v-col direction
    const int ty  = tid >> 4;    // k-col direction

    float acc[4][4];
    #pragma unroll
    for (int i = 0; i < 4; ++i)
        #pragma unroll
        for (int j = 0; j < 4; ++j) acc[i][j] = 0.f;

    for (int t0 = 0; t0 < 256; t0 += 32) {
        #pragma unroll
        for (int r = 0; r < 2; ++r) {
            int idx = tid + 256 * r;     // 0..511
            int row = idx >> 4;          // 0..31
            int c4  = idx & 15;          // 0..15
            *(float4*)&Ks[row][c4 * 4] = *(const float4*)&Kb[(size_t)(t0 + row) * DKH + c4 * 4];
            *(float4*)&Vs[row][c4 * 4] = *(const float4*)&Vb[(size_t)(t0 + row) * DKH + c4 * 4];
        }
        __syncthreads();
        #pragma unroll
        for (int tt = 0; tt < 32; ++tt) {
            float4 ka = *(const float4*)&Ks[tt][ty * 4];
            float4 va = *(const float4*)&Vs[tt][tx * 4];
            float a[4] = {ka.x, ka.y, ka.z, ka.w};
            float v[4] = {va.x, va.y, va.z, va.w};
            #pragma unroll
            for (int i = 0; i < 4; ++i)
                #pragma unroll
                for (int j = 0; j < 4; ++j)
                    acc[i][j] += a[i] * v[j];
        }
        __syncthreads();
    }

    float* Mo = Mpart + ((size_t)p * 8 + chunk) * 4096;
    #pragma unroll
    for (int i = 0; i < 4; ++i)
        #pragma unroll
        for (int j = 0; j < 4; ++j)
            Mo[(ty * 4 + i) * 64 + tx * 4 + j] = acc[i][j];
}

// ---------------------------------------------------------------------------
// Phase B: per (b,h) pair + 256-row chunk: T = Q_h @ (SCALE * M), softmax over
// the 64-wide last axis (exactly one wave per row), write MH.
// grid (8 chunks, 24 pairs).
// ---------------------------------------------------------------------------
__global__ __launch_bounds__(256, 1) void attn_rows(
    const float* __restrict__ Qbuf, const float* __restrict__ Mpart,
    float* __restrict__ MH)
{
    const int chunk = blockIdx.x;
    const int p     = blockIdx.y;
    const int b = p / NHEAD, h = p % NHEAD;
    const float* Qb = Qbuf + (size_t)b * PER_BATCH + (size_t)h * PER_HEAD + (size_t)chunk * 256 * DKH;
    float* MHb      = MH   + (size_t)b * PER_BATCH + (size_t)h * PER_HEAD + (size_t)chunk * 256 * DKH;

    __shared__ __align__(16) float SM[64][64];
    __shared__ __align__(16) float Qs[4][64];

    const int tid = threadIdx.x;

    // Reduce 8 chunk-partials of M, scale, stash in LDS.
    const float4* Mp4 = (const float4*)Mpart + (size_t)p * 8192;
    float4* SM4 = (float4*)SM;
    #pragma unroll
    for (int r = 0; r < 4; ++r) {
        int e4 = tid + 256 * r;     // 0..1023
        float4 s = Mp4[e4];
        #pragma unroll
        for (int c = 1; c < 8; ++c) {
            float4 t = Mp4[(size_t)c * 1024 + e4];
            s.x += t.x; s.y += t.y; s.z += t.z; s.w += t.w;
        }
        s.x *= ATT_SCALE; s.y *= ATT_SCALE; s.z *= ATT_SCALE; s.w *= ATT_SCALE;
        SM4[e4] = s;
    }
    __syncthreads();

    const int lane = tid & 63;
    const int rl   = tid >> 6;   // 0..3: row within group; one wave per row

    for (int r0 = 0; r0 < 256; r0 += 4) {
        __syncthreads();   // protect Qs reuse
        Qs[rl][lane] = Qb[(size_t)(r0 + rl) * DKH + lane];
        __syncthreads();

        float tv = 0.f;
        #pragma unroll
        for (int k = 0; k < 64; ++k)
            tv += Qs[rl][k] * SM[k][lane];

        // softmax across the 64 lanes of this wave
        float mx = tv;
        #pragma unroll
        for (int off = 32; off > 0; off >>= 1)
            mx = fmaxf(mx, __shfl_xor(mx, off, 64));
        float e = __expf(tv - mx);
        float sm = e;
        #pragma unroll
        for (int off = 32; off > 0; off >>= 1)
            sm += __shfl_xor(sm, off, 64);

        MHb[(size_t)(r0 + rl) * DKH + lane] = e / sm;
    }
}

// ---------------------------------------------------------------------------
extern "C" void kernel_launch(void* const* d_in, const int* in_sizes, int n_in,
                              void* d_out, int out_size, void* d_ws, size_t ws_size,
                              hipStream_t stream)
{
    const float* x  = (const float*)d_in[0];
    const float* Wq = (const float*)d_in[1];
    const float* bq = (const float*)d_in[2];
    const float* Wk = (const float*)d_in[3];
    const float* bk = (const float*)d_in[4];
    const float* Wv = (const float*)d_in[5];
    const float* bv = (const float*)d_in[6];
    const float* Wo = (const float*)d_in[7];
    const float* bo = (const float*)d_in[8];
    const float* Wf = (const float*)d_in[9];
    const float* bf = (const float*)d_in[10];
    float* out = (float*)d_out;
    float* ws  = (float*)d_ws;

    // Workspace layout (floats), with aliasing:
    //   [0]        Q            (4096*768)
    //   [3145728]  K  -> later Y1
    //   [6291456]  V  -> later MH
    //   [9437184]  Mpart        (24*8*64*64 = 786432)
    float* Q  = ws;
    float* Kb = ws + 3145728;
    float* Vb = ws + 6291456;
    float* Mp = ws + 9437184;
    float* Y1 = Kb;   // K dead after kv_outer
    float* MH = Vb;   // V dead after kv_outer

    dim3 blk(256);
    // Fused QKV projection
    gemm128<<<dim3(32, 6, 3), blk, 0, stream>>>(x, Wq, Wk, Wv, bq, bk, bv, Q, Kb, Vb);
    // Attention core: M = K^T V (split-t partials), then Q @ (SCALE*M) + softmax
    kv_outer<<<dim3(8, 24), blk, 0, stream>>>(Kb, Vb, Mp);
    attn_rows<<<dim3(8, 24), blk, 0, stream>>>(Q, Mp, MH);
    // Output projections
    gemm128<<<dim3(32, 6, 1), blk, 0, stream>>>(MH, Wo, Wo, Wo, bo, bo, bo, Y1, Y1, Y1);
    gemm128<<<dim3(32, 6, 1), blk, 0, stream>>>(Y1, Wf, Wf, Wf, bf, bf, bf, out, out, out);
}

// Round 2
// 290.657 us; speedup vs baseline: 2.0995x; 2.0995x over previous
//
#include <hip/hip_runtime.h>
#include <math.h>

typedef unsigned short u16;
typedef unsigned int   u32;
typedef __attribute__((ext_vector_type(8))) short bf16x8;
typedef __attribute__((ext_vector_type(4))) float f32x4;

#define DMODEL 768
#define SEQ    2048
#define BATCH  2
#define NHEAD  12
#define DKH    64
#define PER_BATCH (SEQ*DMODEL)
#define PER_HEAD  (SEQ*DKH)
#define ATT_SCALE 0.125f

__device__ inline u16 f2bf(float f) {
    u32 u = __float_as_uint(f);
    u32 r = (u + 0x7FFFu + ((u >> 16) & 1u)) >> 16;
    return (u16)r;
}
__device__ inline float bf2f(u16 h) { return __uint_as_float(((u32)h) << 16); }

__device__ inline void async_load16(const void* g, void* l) {
    __builtin_amdgcn_global_load_lds(
        (const __attribute__((address_space(1))) unsigned int*)g,
        (__attribute__((address_space(3))) unsigned int*)l, 16, 0, 0);
}

// ---------------------------------------------------------------------------
// Conversion: z=0 split x -> xh,xl ; z=1..3 split Wq/Wk/Wv -> stacked Wh3,Wl3 ;
// z=4 cast Wo -> Woh ; z=5 cast Wf -> Wfh.
// ---------------------------------------------------------------------------
__global__ void conv_all(const float* __restrict__ x,
                         const float* __restrict__ Wq, const float* __restrict__ Wk,
                         const float* __restrict__ Wv, const float* __restrict__ Wo,
                         const float* __restrict__ Wf,
                         u16* xh, u16* xl, u16* Wh3, u16* Wl3, u16* Woh, u16* Wfh)
{
    const int z = blockIdx.y;
    const float* src; u16* hi; u16* lo; int n;
    switch (z) {
        case 0: src = x;  hi = xh;            lo = xl;            n = 3145728; break;
        case 1: src = Wq; hi = Wh3;           lo = Wl3;           n = 589824;  break;
        case 2: src = Wk; hi = Wh3 + 589824;  lo = Wl3 + 589824;  n = 589824;  break;
        case 3: src = Wv; hi = Wh3 + 1179648; lo = Wl3 + 1179648; n = 589824;  break;
        case 4: src = Wo; hi = Woh;           lo = nullptr;       n = 589824;  break;
        default:src = Wf; hi = Wfh;           lo = nullptr;       n = 589824;  break;
    }
    const int n4 = n >> 2;
    for (int i = blockIdx.x * blockDim.x + threadIdx.x; i < n4; i += gridDim.x * blockDim.x) {
        float4 v = ((const float4*)src)[i];
        u16 h0 = f2bf(v.x), h1 = f2bf(v.y), h2 = f2bf(v.z), h3 = f2bf(v.w);
        uint2 hp; hp.x = (u32)h0 | ((u32)h1 << 16); hp.y = (u32)h2 | ((u32)h3 << 16);
        ((uint2*)hi)[i] = hp;
        if (lo) {
            u16 l0 = f2bf(v.x - bf2f(h0)), l1 = f2bf(v.y - bf2f(h1));
            u16 l2 = f2bf(v.z - bf2f(h2)), l3 = f2bf(v.w - bf2f(h3));
            uint2 lp; lp.x = (u32)l0 | ((u32)l1 << 16); lp.y = (u32)l2 | ((u32)l3 << 16);
            ((uint2*)lo)[i] = lp;
        }
    }
}

// ---------------------------------------------------------------------------
// MFMA GEMM:  C = A @ W^T + bias.  A: 4096xK bf16 (row-major), W: Ntot x K bf16.
// K = 768 per segment; nseg=3 does the bf16x2-split product AhWh+AhWl+AlWh.
// 128x128 tile, BK=32, 256 thr (4 waves, each 64x64 = 4x4 of 16x16x32 MFMA).
// Output column block selects C0/C1/C2 (Ntot = gridDim.y*128; 768 cols each).
// ---------------------------------------------------------------------------
__global__ __launch_bounds__(256, 2) void mfma_gemm(
    const u16* __restrict__ Ah, const u16* __restrict__ Al,
    const u16* __restrict__ Wh, const u16* __restrict__ Wl,
    const float* __restrict__ b0, const float* __restrict__ b1, const float* __restrict__ b2,
    void* __restrict__ C0, void* __restrict__ C1, void* __restrict__ C2,
    int nseg, int out_bf16)
{
    const int tid = threadIdx.x;
    const int w   = tid >> 6;
    const int L   = tid & 63;
    const int wr  = w >> 1, wc = w & 1;
    const int mBase = blockIdx.x * 128;
    const int nBase = blockIdx.y * 128;
    const int sel  = nBase / 768;
    const int nOff = nBase % 768;

    __shared__ __align__(16) u16 As[128 * 32];
    __shared__ __align__(16) u16 Bs[128 * 32];

    f32x4 acc[4][4];
    #pragma unroll
    for (int i = 0; i < 4; ++i)
        #pragma unroll
        for (int j = 0; j < 4; ++j)
            acc[i][j] = (f32x4){0.f, 0.f, 0.f, 0.f};

    const int srow = L >> 2;          // 0..15 row within 16-row chunk
    const int scol = (L & 3) * 8;     // k-element offset

    for (int seg = 0; seg < nseg; ++seg) {
        const u16* Aseg = (seg == 2) ? Al : Ah;
        const u16* Wseg = (seg == 1) ? Wl : Wh;
        for (int kb = 0; kb < 768; kb += 32) {
            #pragma unroll
            for (int i = 0; i < 2; ++i) {
                const int ch = w * 2 + i;                 // 16-row chunk id 0..7
                const int rA = mBase + ch * 16 + srow;
                async_load16(&Aseg[(size_t)rA * 768 + kb + scol], &As[ch * 512]);
                const int rB = nBase + ch * 16 + srow;
                async_load16(&Wseg[(size_t)rB * 768 + kb + scol], &Bs[ch * 512]);
            }
            __syncthreads();
            const int rin = L & 15, kq = (L >> 4) * 8;
            bf16x8 af[4], bfr[4];
            #pragma unroll
            for (int i = 0; i < 4; ++i)
                af[i] = *(const bf16x8*)&As[(wr * 64 + i * 16 + rin) * 32 + kq];
            #pragma unroll
            for (int j = 0; j < 4; ++j)
                bfr[j] = *(const bf16x8*)&Bs[(wc * 64 + j * 16 + rin) * 32 + kq];
            #pragma unroll
            for (int i = 0; i < 4; ++i)
                #pragma unroll
                for (int j = 0; j < 4; ++j)
                    acc[i][j] = __builtin_amdgcn_mfma_f32_16x16x32_bf16(af[i], bfr[j], acc[i][j], 0, 0, 0);
            __syncthreads();
        }
    }

    const float* bsel = (sel == 0) ? b0 : ((sel == 1) ? b1 : b2);
    void* Csel = (sel == 0) ? C0 : ((sel == 1) ? C1 : C2);
    const int rin = L & 15, rq = (L >> 4) * 4;

    #pragma unroll
    for (int j = 0; j < 4; ++j) {
        const int c = nOff + wc * 64 + j * 16 + rin;
        const float bv = bsel[c];
        #pragma unroll
        for (int i = 0; i < 4; ++i) {
            const int r0 = mBase + wr * 64 + i * 16 + rq;
            #pragma unroll
            for (int reg = 0; reg < 4; ++reg) {
                const float v = acc[i][j][reg] + bv;
                if (out_bf16) ((u16*)Csel)[(size_t)(r0 + reg) * 768 + c] = f2bf(v);
                else          ((float*)Csel)[(size_t)(r0 + reg) * 768 + c] = v;
            }
        }
    }
}

// ---------------------------------------------------------------------------
// Phase A: per (b,h) pair, partial M = K_h^T V_h over a 256-row t-chunk. fp32.
// ---------------------------------------------------------------------------
__global__ __launch_bounds__(256, 1) void kv_outer(
    const float* __restrict__ Kbuf, const float* __restrict__ Vbuf,
    float* __restrict__ Mpart)
{
    const int chunk = blockIdx.x;
    const int p     = blockIdx.y;
    const int b = p / NHEAD, h = p % NHEAD;
    const float* Kb = Kbuf + (size_t)b * PER_BATCH + (size_t)h * PER_HEAD + (size_t)chunk * 256 * DKH;
    const float* Vb = Vbuf + (size_t)b * PER_BATCH + (size_t)h * PER_HEAD + (size_t)chunk * 256 * DKH;

    __shared__ __align__(16) float Ks[32][64];
    __shared__ __align__(16) float Vs[32][64];

    const int tid = threadIdx.x;
    const int tx  = tid & 15;
    const int ty  = tid >> 4;

    float acc[4][4];
    #pragma unroll
    for (int i = 0; i < 4; ++i)
        #pragma unroll
        for (int j = 0; j < 4; ++j) acc[i][j] = 0.f;

    for (int t0 = 0; t0 < 256; t0 += 32) {
        #pragma unroll
        for (int r = 0; r < 2; ++r) {
            int idx = tid + 256 * r;
            int row = idx >> 4;
            int c4  = idx & 15;
            *(float4*)&Ks[row][c4 * 4] = *(const float4*)&Kb[(size_t)(t0 + row) * DKH + c4 * 4];
            *(float4*)&Vs[row][c4 * 4] = *(const float4*)&Vb[(size_t)(t0 + row) * DKH + c4 * 4];
        }
        __syncthreads();
        #pragma unroll
        for (int tt = 0; tt < 32; ++tt) {
            float4 ka = *(const float4*)&Ks[tt][ty * 4];
            float4 va = *(const float4*)&Vs[tt][tx * 4];
            float a[4] = {ka.x, ka.y, ka.z, ka.w};
            float v[4] = {va.x, va.y, va.z, va.w};
            #pragma unroll
            for (int i = 0; i < 4; ++i)
                #pragma unroll
                for (int j = 0; j < 4; ++j)
                    acc[i][j] += a[i] * v[j];
        }
        __syncthreads();
    }

    float* Mo = Mpart + ((size_t)p * 8 + chunk) * 4096;
    #pragma unroll
    for (int i = 0; i < 4; ++i)
        #pragma unroll
        for (int j = 0; j < 4; ++j)
            Mo[(ty * 4 + i) * 64 + tx * 4 + j] = acc[i][j];
}

// ---------------------------------------------------------------------------
// Phase B: T = Q @ (SCALE*M), softmax over 64-wide axis (one wave per row).
// Writes MH directly as bf16 (feeds the bf16 MFMA projection).
// ---------------------------------------------------------------------------
__global__ __launch_bounds__(256, 1) void attn_rows(
    const float* __restrict__ Qbuf, const float* __restrict__ Mpart,
    u16* __restrict__ MH)
{
    const int chunk = blockIdx.x;
    const int p     = blockIdx.y;
    const int b = p / NHEAD, h = p % NHEAD;
    const float* Qb = Qbuf + (size_t)b * PER_BATCH + (size_t)h * PER_HEAD + (size_t)chunk * 256 * DKH;
    u16* MHb        = MH   + (size_t)b * PER_BATCH + (size_t)h * PER_HEAD + (size_t)chunk * 256 * DKH;

    __shared__ __align__(16) float SM[64][64];
    __shared__ __align__(16) float Qs[4][64];

    const int tid = threadIdx.x;

    const float4* Mp4 = (const float4*)Mpart + (size_t)p * 8192;
    float4* SM4 = (float4*)SM;
    #pragma unroll
    for (int r = 0; r < 4; ++r) {
        int e4 = tid + 256 * r;
        float4 s = Mp4[e4];
        #pragma unroll
        for (int c = 1; c < 8; ++c) {
            float4 t = Mp4[(size_t)c * 1024 + e4];
            s.x += t.x; s.y += t.y; s.z += t.z; s.w += t.w;
        }
        s.x *= ATT_SCALE; s.y *= ATT_SCALE; s.z *= ATT_SCALE; s.w *= ATT_SCALE;
        SM4[e4] = s;
    }
    __syncthreads();

    const int lane = tid & 63;
    const int rl   = tid >> 6;

    for (int r0 = 0; r0 < 256; r0 += 4) {
        __syncthreads();
        Qs[rl][lane] = Qb[(size_t)(r0 + rl) * DKH + lane];
        __syncthreads();

        float tv = 0.f;
        #pragma unroll
        for (int k = 0; k < 64; ++k)
            tv += Qs[rl][k] * SM[k][lane];

        float mx = tv;
        #pragma unroll
        for (int off = 32; off > 0; off >>= 1)
            mx = fmaxf(mx, __shfl_xor(mx, off, 64));
        float e = __expf(tv - mx);
        float sm = e;
        #pragma unroll
        for (int off = 32; off > 0; off >>= 1)
            sm += __shfl_xor(sm, off, 64);

        MHb[(size_t)(r0 + rl) * DKH + lane] = f2bf(e / sm);
    }
}

// ---------------------------------------------------------------------------
extern "C" void kernel_launch(void* const* d_in, const int* in_sizes, int n_in,
                              void* d_out, int out_size, void* d_ws, size_t ws_size,
                              hipStream_t stream)
{
    const float* x  = (const float*)d_in[0];
    const float* Wq = (const float*)d_in[1];
    const float* bq = (const float*)d_in[2];
    const float* Wk = (const float*)d_in[3];
    const float* bk = (const float*)d_in[4];
    const float* Wv = (const float*)d_in[5];
    const float* bv = (const float*)d_in[6];
    const float* Wo = (const float*)d_in[7];
    const float* bo = (const float*)d_in[8];
    const float* Wf = (const float*)d_in[9];
    const float* bf = (const float*)d_in[10];
    float* out = (float*)d_out;

    // Workspace layout:
    //   fp32: Q(3.1M) K(3.1M) V(3.1M) Mpart(0.79M)
    //   u16 : xh(3.1M) xl(3.1M) Wh3(1.77M) Wl3(1.77M) Woh(0.59M) Wfh(0.59M)
    //   alias: MH -> xh, Y1 -> xl  (both dead after the QKV GEMM)
    float* ws_f = (float*)d_ws;
    float* Q  = ws_f;
    float* Kb = ws_f + 3145728;
    float* Vb = ws_f + 6291456;
    float* Mp = ws_f + 9437184;
    u16* ub  = (u16*)(ws_f + 10223616);
    u16* xh  = ub;
    u16* xl  = ub + 3145728;
    u16* Wh3 = ub + 6291456;
    u16* Wl3 = Wh3 + 1769472;
    u16* Woh = Wl3 + 1769472;
    u16* Wfh = Woh + 589824;
    u16* MH  = xh;
    u16* Y1  = xl;

    dim3 blk(256);
    conv_all<<<dim3(128, 6), blk, 0, stream>>>(x, Wq, Wk, Wv, Wo, Wf, xh, xl, Wh3, Wl3, Woh, Wfh);
    // QKV: bf16x2-split MFMA GEMM (3 segments), fp32 out
    mfma_gemm<<<dim3(32, 18), blk, 0, stream>>>(xh, xl, Wh3, Wl3, bq, bk, bv, Q, Kb, Vb, 3, 0);
    // Attention core (fp32)
    kv_outer<<<dim3(8, 24), blk, 0, stream>>>(Kb, Vb, Mp);
    attn_rows<<<dim3(8, 24), blk, 0, stream>>>(Q, Mp, MH);
    // Output projections: plain bf16 MFMA
    mfma_gemm<<<dim3(32, 6), blk, 0, stream>>>(MH, nullptr, Woh, nullptr, bo, bo, bo, Y1, Y1, Y1, 1, 1);
    mfma_gemm<<<dim3(32, 6), blk, 0, stream>>>(Y1, nullptr, Wfh, nullptr, bf, bf, bf, out, out, out, 1, 0);
}

// Round 3
// 227.028 us; speedup vs baseline: 2.6880x; 1.2803x over previous
//
#include <hip/hip_runtime.h>
#include <math.h>

typedef unsigned short u16;
typedef unsigned int   u32;
typedef __attribute__((ext_vector_type(8))) short bf16x8;
typedef __attribute__((ext_vector_type(4))) float f32x4;

#define DMODEL 768
#define SEQ    2048
#define BATCH  2
#define NHEAD  12
#define DKH    64
#define PER_BATCH (SEQ*DMODEL)
#define PER_HEAD  (SEQ*DKH)
#define ATT_SCALE 0.125f

__device__ inline u16 f2bf(float f) {
    u32 u = __float_as_uint(f);
    u32 r = (u + 0x7FFFu + ((u >> 16) & 1u)) >> 16;
    return (u16)r;
}
__device__ inline float bf2f(u16 h) { return __uint_as_float(((u32)h) << 16); }

__device__ inline void async_load16(const void* g, void* l) {
    __builtin_amdgcn_global_load_lds(
        (const __attribute__((address_space(1))) unsigned int*)g,
        (__attribute__((address_space(3))) unsigned int*)l, 16, 0, 0);
}

// ---------------------------------------------------------------------------
// Conversion: z=0 split x -> xh,xl ; z=1..3 split Wq/Wk/Wv -> stacked Wh3,Wl3 ;
// z=4 cast Wo -> Woh ; z=5 cast Wf -> Wfh.
// ---------------------------------------------------------------------------
__global__ void conv_all(const float* __restrict__ x,
                         const float* __restrict__ Wq, const float* __restrict__ Wk,
                         const float* __restrict__ Wv, const float* __restrict__ Wo,
                         const float* __restrict__ Wf,
                         u16* xh, u16* xl, u16* Wh3, u16* Wl3, u16* Woh, u16* Wfh)
{
    const int z = blockIdx.y;
    const float* src; u16* hi; u16* lo; int n;
    switch (z) {
        case 0: src = x;  hi = xh;            lo = xl;            n = 3145728; break;
        case 1: src = Wq; hi = Wh3;           lo = Wl3;           n = 589824;  break;
        case 2: src = Wk; hi = Wh3 + 589824;  lo = Wl3 + 589824;  n = 589824;  break;
        case 3: src = Wv; hi = Wh3 + 1179648; lo = Wl3 + 1179648; n = 589824;  break;
        case 4: src = Wo; hi = Woh;           lo = nullptr;       n = 589824;  break;
        default:src = Wf; hi = Wfh;           lo = nullptr;       n = 589824;  break;
    }
    const int n4 = n >> 2;
    for (int i = blockIdx.x * blockDim.x + threadIdx.x; i < n4; i += gridDim.x * blockDim.x) {
        float4 v = ((const float4*)src)[i];
        u16 h0 = f2bf(v.x), h1 = f2bf(v.y), h2 = f2bf(v.z), h3 = f2bf(v.w);
        uint2 hp; hp.x = (u32)h0 | ((u32)h1 << 16); hp.y = (u32)h2 | ((u32)h3 << 16);
        ((uint2*)hi)[i] = hp;
        if (lo) {
            u16 l0 = f2bf(v.x - bf2f(h0)), l1 = f2bf(v.y - bf2f(h1));
            u16 l2 = f2bf(v.z - bf2f(h2)), l3 = f2bf(v.w - bf2f(h3));
            uint2 lp; lp.x = (u32)l0 | ((u32)l1 << 16); lp.y = (u32)l2 | ((u32)l3 << 16);
            ((uint2*)lo)[i] = lp;
        }
    }
}

// ---------------------------------------------------------------------------
// MFMA GEMM:  C = A @ W^T + bias.  A: 4096xK bf16 (row-major), W: Ntot x K bf16.
// nseg=3 does the bf16x2-split product AhWh+AhWl+AlWh.
// 128x128 tile, BK=32, 256 thr (4 waves, each 64x64 = 4x4 of 16x16x32 MFMA).
// ---------------------------------------------------------------------------
__global__ __launch_bounds__(256, 2) void mfma_gemm(
    const u16* __restrict__ Ah, const u16* __restrict__ Al,
    const u16* __restrict__ Wh, const u16* __restrict__ Wl,
    const float* __restrict__ b0, const float* __restrict__ b1, const float* __restrict__ b2,
    void* __restrict__ C0, void* __restrict__ C1, void* __restrict__ C2,
    int nseg, int out_bf16)
{
    const int tid = threadIdx.x;
    const int w   = tid >> 6;
    const int L   = tid & 63;
    const int wr  = w >> 1, wc = w & 1;
    const int mBase = blockIdx.x * 128;
    const int nBase = blockIdx.y * 128;
    const int sel  = nBase / 768;
    const int nOff = nBase % 768;

    __shared__ __align__(16) u16 As[128 * 32];
    __shared__ __align__(16) u16 Bs[128 * 32];

    f32x4 acc[4][4];
    #pragma unroll
    for (int i = 0; i < 4; ++i)
        #pragma unroll
        for (int j = 0; j < 4; ++j)
            acc[i][j] = (f32x4){0.f, 0.f, 0.f, 0.f};

    const int srow = L >> 2;
    const int scol = (L & 3) * 8;

    for (int seg = 0; seg < nseg; ++seg) {
        const u16* Aseg = (seg == 2) ? Al : Ah;
        const u16* Wseg = (seg == 1) ? Wl : Wh;
        for (int kb = 0; kb < 768; kb += 32) {
            #pragma unroll
            for (int i = 0; i < 2; ++i) {
                const int ch = w * 2 + i;
                const int rA = mBase + ch * 16 + srow;
                async_load16(&Aseg[(size_t)rA * 768 + kb + scol], &As[ch * 512]);
                const int rB = nBase + ch * 16 + srow;
                async_load16(&Wseg[(size_t)rB * 768 + kb + scol], &Bs[ch * 512]);
            }
            __syncthreads();
            const int rin = L & 15, kq = (L >> 4) * 8;
            bf16x8 af[4], bfr[4];
            #pragma unroll
            for (int i = 0; i < 4; ++i)
                af[i] = *(const bf16x8*)&As[(wr * 64 + i * 16 + rin) * 32 + kq];
            #pragma unroll
            for (int j = 0; j < 4; ++j)
                bfr[j] = *(const bf16x8*)&Bs[(wc * 64 + j * 16 + rin) * 32 + kq];
            #pragma unroll
            for (int i = 0; i < 4; ++i)
                #pragma unroll
                for (int j = 0; j < 4; ++j)
                    acc[i][j] = __builtin_amdgcn_mfma_f32_16x16x32_bf16(af[i], bfr[j], acc[i][j], 0, 0, 0);
            __syncthreads();
        }
    }

    const float* bsel = (sel == 0) ? b0 : ((sel == 1) ? b1 : b2);
    void* Csel = (sel == 0) ? C0 : ((sel == 1) ? C1 : C2);
    const int rin = L & 15, rq = (L >> 4) * 4;

    #pragma unroll
    for (int j = 0; j < 4; ++j) {
        const int c = nOff + wc * 64 + j * 16 + rin;
        const float bv = bsel[c];
        #pragma unroll
        for (int i = 0; i < 4; ++i) {
            const int r0 = mBase + wr * 64 + i * 16 + rq;
            #pragma unroll
            for (int reg = 0; reg < 4; ++reg) {
                const float v = acc[i][j][reg] + bv;
                if (out_bf16) ((u16*)Csel)[(size_t)(r0 + reg) * 768 + c] = f2bf(v);
                else          ((float*)Csel)[(size_t)(r0 + reg) * 768 + c] = v;
            }
        }
    }
}

// ---------------------------------------------------------------------------
// Phase A: per (b,h) pair, partial M = K_h^T V_h over a 256-row t-chunk. fp32.
// ---------------------------------------------------------------------------
__global__ __launch_bounds__(256, 1) void kv_outer(
    const float* __restrict__ Kbuf, const float* __restrict__ Vbuf,
    float* __restrict__ Mpart)
{
    const int chunk = blockIdx.x;
    const int p     = blockIdx.y;
    const int b = p / NHEAD, h = p % NHEAD;
    const float* Kb = Kbuf + (size_t)b * PER_BATCH + (size_t)h * PER_HEAD + (size_t)chunk * 256 * DKH;
    const float* Vb = Vbuf + (size_t)b * PER_BATCH + (size_t)h * PER_HEAD + (size_t)chunk * 256 * DKH;

    __shared__ __align__(16) float Ks[32][64];
    __shared__ __align__(16) float Vs[32][64];

    const int tid = threadIdx.x;
    const int tx  = tid & 15;
    const int ty  = tid >> 4;

    float acc[4][4];
    #pragma unroll
    for (int i = 0; i < 4; ++i)
        #pragma unroll
        for (int j = 0; j < 4; ++j) acc[i][j] = 0.f;

    for (int t0 = 0; t0 < 256; t0 += 32) {
        #pragma unroll
        for (int r = 0; r < 2; ++r) {
            int idx = tid + 256 * r;
            int row = idx >> 4;
            int c4  = idx & 15;
            *(float4*)&Ks[row][c4 * 4] = *(const float4*)&Kb[(size_t)(t0 + row) * DKH + c4 * 4];
            *(float4*)&Vs[row][c4 * 4] = *(const float4*)&Vb[(size_t)(t0 + row) * DKH + c4 * 4];
        }
        __syncthreads();
        #pragma unroll
        for (int tt = 0; tt < 32; ++tt) {
            float4 ka = *(const float4*)&Ks[tt][ty * 4];
            float4 va = *(const float4*)&Vs[tt][tx * 4];
            float a[4] = {ka.x, ka.y, ka.z, ka.w};
            float v[4] = {va.x, va.y, va.z, va.w};
            #pragma unroll
            for (int i = 0; i < 4; ++i)
                #pragma unroll
                for (int j = 0; j < 4; ++j)
                    acc[i][j] += a[i] * v[j];
        }
        __syncthreads();
    }

    float* Mo = Mpart + ((size_t)p * 8 + chunk) * 4096;
    #pragma unroll
    for (int i = 0; i < 4; ++i)
        #pragma unroll
        for (int j = 0; j < 4; ++j)
            Mo[(ty * 4 + i) * 64 + tx * 4 + j] = acc[i][j];
}

// ---------------------------------------------------------------------------
// Reduce the 8 chunk-partials of M once per pair, pre-scaled. 24 blocks.
// ---------------------------------------------------------------------------
__global__ __launch_bounds__(256, 1) void reduce_M(
    const float* __restrict__ Mpart, float* __restrict__ Mred)
{
    const int p = blockIdx.x;
    const float4* Mp4 = (const float4*)Mpart + (size_t)p * 8192;
    float4* Mr4 = (float4*)Mred + (size_t)p * 1024;
    #pragma unroll
    for (int r = 0; r < 4; ++r) {
        int e4 = threadIdx.x + 256 * r;
        float4 s = Mp4[e4];
        #pragma unroll
        for (int c = 1; c < 8; ++c) {
            float4 t = Mp4[(size_t)c * 1024 + e4];
            s.x += t.x; s.y += t.y; s.z += t.z; s.w += t.w;
        }
        s.x *= ATT_SCALE; s.y *= ATT_SCALE; s.z *= ATT_SCALE; s.w *= ATT_SCALE;
        Mr4[e4] = s;
    }
}

// ---------------------------------------------------------------------------
// Phase B as register-tiled GEMM + fused softmax.
// Block = 64 rows x 64 cols of T = Q @ Mred for one (b,h); 256 threads,
// 4x4 micro-tile each; ONE barrier; softmax via 16-lane xor-shuffles.
// grid (32 chunks, 24 pairs).
// ---------------------------------------------------------------------------
__global__ __launch_bounds__(256, 2) void attn_gemm(
    const float* __restrict__ Qbuf, const float* __restrict__ Mred,
    u16* __restrict__ MH)
{
    const int chunk = blockIdx.x;   // 0..31 (64 rows each)
    const int p     = blockIdx.y;   // 0..23
    const int b = p / NHEAD, h = p % NHEAD;
    const float* Qb = Qbuf + (size_t)b * PER_BATCH + (size_t)h * PER_HEAD + (size_t)chunk * 64 * DKH;
    u16* MHb        = MH   + (size_t)b * PER_BATCH + (size_t)h * PER_HEAD + (size_t)chunk * 64 * DKH;

    __shared__ float QsT[64][65];            // transposed Q tile, pad 65
    __shared__ __align__(16) float SM[64][64];

    const int tid = threadIdx.x;

    // Stage SM (already scaled) and Q (transposed).
    const float4* M4 = (const float4*)(Mred + (size_t)p * 4096);
    float4* SM4 = (float4*)SM;
    #pragma unroll
    for (int r = 0; r < 4; ++r) {
        int e4 = tid + 256 * r;              // 0..1023
        SM4[e4] = M4[e4];
        int row = e4 >> 4, c4 = e4 & 15;
        float4 v = *(const float4*)&Qb[(size_t)row * DKH + c4 * 4];
        QsT[c4 * 4 + 0][row] = v.x; QsT[c4 * 4 + 1][row] = v.y;
        QsT[c4 * 4 + 2][row] = v.z; QsT[c4 * 4 + 3][row] = v.w;
    }
    __syncthreads();

    const int tx = tid & 15;     // col group (cols tx*4..+3)
    const int ty = tid >> 4;     // row group (rows ty*4..+3)

    float acc[4][4];
    #pragma unroll
    for (int i = 0; i < 4; ++i)
        #pragma unroll
        for (int j = 0; j < 4; ++j) acc[i][j] = 0.f;

    #pragma unroll 4
    for (int k = 0; k < 64; ++k) {
        float4 bv = *(const float4*)&SM[k][tx * 4];
        float a0 = QsT[k][ty * 4 + 0];
        float a1 = QsT[k][ty * 4 + 1];
        float a2 = QsT[k][ty * 4 + 2];
        float a3 = QsT[k][ty * 4 + 3];
        float bb[4] = {bv.x, bv.y, bv.z, bv.w};
        float aa[4] = {a0, a1, a2, a3};
        #pragma unroll
        for (int i = 0; i < 4; ++i)
            #pragma unroll
            for (int j = 0; j < 4; ++j)
                acc[i][j] += aa[i] * bb[j];
    }

    // Softmax over the 64-wide axis: each row lives in 16 consecutive lanes x 4 regs.
    #pragma unroll
    for (int i = 0; i < 4; ++i) {
        float m = fmaxf(fmaxf(acc[i][0], acc[i][1]), fmaxf(acc[i][2], acc[i][3]));
        #pragma unroll
        for (int off = 1; off < 16; off <<= 1)
            m = fmaxf(m, __shfl_xor(m, off, 64));
        float e0 = __expf(acc[i][0] - m), e1 = __expf(acc[i][1] - m);
        float e2 = __expf(acc[i][2] - m), e3 = __expf(acc[i][3] - m);
        float s = (e0 + e1) + (e2 + e3);
        #pragma unroll
        for (int off = 1; off < 16; off <<= 1)
            s += __shfl_xor(s, off, 64);
        float inv = 1.f / s;
        u16 o0 = f2bf(e0 * inv), o1 = f2bf(e1 * inv);
        u16 o2 = f2bf(e2 * inv), o3 = f2bf(e3 * inv);
        uint2 pk; pk.x = (u32)o0 | ((u32)o1 << 16); pk.y = (u32)o2 | ((u32)o3 << 16);
        const int row = ty * 4 + i;
        *(uint2*)&MHb[(size_t)row * DKH + tx * 4] = pk;
    }
}

// ---------------------------------------------------------------------------
extern "C" void kernel_launch(void* const* d_in, const int* in_sizes, int n_in,
                              void* d_out, int out_size, void* d_ws, size_t ws_size,
                              hipStream_t stream)
{
    const float* x  = (const float*)d_in[0];
    const float* Wq = (const float*)d_in[1];
    const float* bq = (const float*)d_in[2];
    const float* Wk = (const float*)d_in[3];
    const float* bk = (const float*)d_in[4];
    const float* Wv = (const float*)d_in[5];
    const float* bv = (const float*)d_in[6];
    const float* Wo = (const float*)d_in[7];
    const float* bo = (const float*)d_in[8];
    const float* Wf = (const float*)d_in[9];
    const float* bf = (const float*)d_in[10];
    float* out = (float*)d_out;

    // Workspace layout (floats):
    //   Q(3.1M) K(3.1M) V(3.1M) Mpart(0.79M) Mred(98K)
    //   then u16: xh(3.1M) xl(3.1M) Wh3(1.77M) Wl3(1.77M) Woh(0.59M) Wfh(0.59M)
    //   alias: MH -> xh, Y1 -> xl  (dead after QKV GEMM)
    float* ws_f = (float*)d_ws;
    float* Q   = ws_f;
    float* Kb  = ws_f + 3145728;
    float* Vb  = ws_f + 6291456;
    float* Mp  = ws_f + 9437184;
    float* Mrd = ws_f + 10223616;
    u16* ub  = (u16*)(ws_f + 10321920);
    u16* xh  = ub;
    u16* xl  = ub + 3145728;
    u16* Wh3 = ub + 6291456;
    u16* Wl3 = Wh3 + 1769472;
    u16* Woh = Wl3 + 1769472;
    u16* Wfh = Woh + 589824;
    u16* MH  = xh;
    u16* Y1  = xl;

    dim3 blk(256);
    conv_all<<<dim3(128, 6), blk, 0, stream>>>(x, Wq, Wk, Wv, Wo, Wf, xh, xl, Wh3, Wl3, Woh, Wfh);
    // QKV: bf16x2-split MFMA GEMM (3 segments), fp32 out
    mfma_gemm<<<dim3(32, 18), blk, 0, stream>>>(xh, xl, Wh3, Wl3, bq, bk, bv, Q, Kb, Vb, 3, 0);
    // Attention core (fp32)
    kv_outer<<<dim3(8, 24), blk, 0, stream>>>(Kb, Vb, Mp);
    reduce_M<<<dim3(24), blk, 0, stream>>>(Mp, Mrd);
    attn_gemm<<<dim3(32, 24), blk, 0, stream>>>(Q, Mrd, MH);
    // Output projections: plain bf16 MFMA
    mfma_gemm<<<dim3(32, 6), blk, 0, stream>>>(MH, nullptr, Woh, nullptr, bo, bo, bo, Y1, Y1, Y1, 1, 1);
    mfma_gemm<<<dim3(32, 6), blk, 0, stream>>>(Y1, nullptr, Wfh, nullptr, bf, bf, bf, out, out, out, 1, 0);
}

// Round 4
// 221.716 us; speedup vs baseline: 2.7524x; 1.0240x over previous
//
#include <hip/hip_runtime.h>
#include <math.h>

typedef unsigned short u16;
typedef unsigned int   u32;
typedef __attribute__((ext_vector_type(8))) short bf16x8;
typedef __attribute__((ext_vector_type(4))) float f32x4;

#define DMODEL 768
#define SEQ    2048
#define BATCH  2
#define NHEAD  12
#define DKH    64
#define PER_BATCH (SEQ*DMODEL)
#define PER_HEAD  (SEQ*DKH)
#define ATT_SCALE 0.125f

__device__ inline u16 f2bf(float f) {
    u32 u = __float_as_uint(f);
    u32 r = (u + 0x7FFFu + ((u >> 16) & 1u)) >> 16;
    return (u16)r;
}
__device__ inline float bf2f(u16 h) { return __uint_as_float(((u32)h) << 16); }

__device__ inline void async_load16(const void* g, void* l) {
    __builtin_amdgcn_global_load_lds(
        (const __attribute__((address_space(1))) unsigned int*)g,
        (__attribute__((address_space(3))) unsigned int*)l, 16, 0, 0);
}

// ---------------------------------------------------------------------------
// Conversion: z=0 split x -> xh,xl ; z=1..3 split Wq/Wk/Wv -> stacked Wh3,Wl3 ;
// z=4 cast Wf -> Wfh.
// ---------------------------------------------------------------------------
__global__ void conv_all(const float* __restrict__ x,
                         const float* __restrict__ Wq, const float* __restrict__ Wk,
                         const float* __restrict__ Wv, const float* __restrict__ Wf,
                         u16* xh, u16* xl, u16* Wh3, u16* Wl3, u16* Wfh)
{
    const int z = blockIdx.y;
    const float* src; u16* hi; u16* lo; int n;
    switch (z) {
        case 0: src = x;  hi = xh;            lo = xl;            n = 3145728; break;
        case 1: src = Wq; hi = Wh3;           lo = Wl3;           n = 589824;  break;
        case 2: src = Wk; hi = Wh3 + 589824;  lo = Wl3 + 589824;  n = 589824;  break;
        case 3: src = Wv; hi = Wh3 + 1179648; lo = Wl3 + 1179648; n = 589824;  break;
        default:src = Wf; hi = Wfh;           lo = nullptr;       n = 589824;  break;
    }
    const int n4 = n >> 2;
    for (int i = blockIdx.x * blockDim.x + threadIdx.x; i < n4; i += gridDim.x * blockDim.x) {
        float4 v = ((const float4*)src)[i];
        u16 h0 = f2bf(v.x), h1 = f2bf(v.y), h2 = f2bf(v.z), h3 = f2bf(v.w);
        uint2 hp; hp.x = (u32)h0 | ((u32)h1 << 16); hp.y = (u32)h2 | ((u32)h3 << 16);
        ((uint2*)hi)[i] = hp;
        if (lo) {
            u16 l0 = f2bf(v.x - bf2f(h0)), l1 = f2bf(v.y - bf2f(h1));
            u16 l2 = f2bf(v.z - bf2f(h2)), l3 = f2bf(v.w - bf2f(h3));
            uint2 lp; lp.x = (u32)l0 | ((u32)l1 << 16); lp.y = (u32)l2 | ((u32)l3 << 16);
            ((uint2*)lo)[i] = lp;
        }
    }
}

// ---------------------------------------------------------------------------
// 32x32-tile LDS transpose: WoT[j,k] = bf16(Wo[k,j]).
// ---------------------------------------------------------------------------
__global__ __launch_bounds__(256, 2) void transpose_wo(
    const float* __restrict__ Wo, u16* __restrict__ WoT)
{
    __shared__ u16 S[32][33];
    const int bi = blockIdx.x, bj = blockIdx.y;
    const int r  = threadIdx.x >> 3;     // 0..31
    const int c4 = threadIdx.x & 7;      // 0..7
    float4 v = *(const float4*)&Wo[(size_t)(bi * 32 + r) * 768 + bj * 32 + c4 * 4];
    S[c4 * 4 + 0][r] = f2bf(v.x); S[c4 * 4 + 1][r] = f2bf(v.y);
    S[c4 * 4 + 2][r] = f2bf(v.z); S[c4 * 4 + 3][r] = f2bf(v.w);
    __syncthreads();
    u16 o0 = S[r][c4 * 4 + 0], o1 = S[r][c4 * 4 + 1];
    u16 o2 = S[r][c4 * 4 + 2], o3 = S[r][c4 * 4 + 3];
    uint2 pk; pk.x = (u32)o0 | ((u32)o1 << 16); pk.y = (u32)o2 | ((u32)o3 << 16);
    *(uint2*)&WoT[(size_t)(bj * 32 + r) * 768 + bi * 32 + c4 * 4] = pk;
}

// ---------------------------------------------------------------------------
// bc = Wf @ bo + bf (one wave per output row); block 0 also zeroes `zeros`.
// ---------------------------------------------------------------------------
__global__ void bc_kernel(const float* __restrict__ Wf, const float* __restrict__ bo,
                          const float* __restrict__ bfb, float* __restrict__ bc,
                          float* __restrict__ zeros)
{
    if (blockIdx.x == 0) {
        zeros[threadIdx.x] = 0.f; zeros[threadIdx.x + 256] = 0.f; zeros[threadIdx.x + 512] = 0.f;
    }
    const int wid  = (blockIdx.x * 256 + threadIdx.x) >> 6;   // 0..767
    const int lane = threadIdx.x & 63;
    float s = 0.f;
    const float* row = Wf + (size_t)wid * 768;
    #pragma unroll
    for (int t = 0; t < 12; ++t) s += row[lane + 64 * t] * bo[lane + 64 * t];
    #pragma unroll
    for (int off = 32; off > 0; off >>= 1) s += __shfl_xor(s, off, 64);
    if (lane == 0) bc[wid] = s + bfb[wid];
}

// ---------------------------------------------------------------------------
// MFMA GEMM:  C = A @ W^T + bias.  A: Mrows x 768 bf16, W: Ntot x 768 bf16.
// nseg=3 does the bf16x2-split product AhWh+AhWl+AlWh.
// 128x128 tile, BK=32, 256 thr (4 waves, each 64x64 = 4x4 of 16x16x32 MFMA).
// LDS XOR-swizzle: lane L stages k-group (L&3)^((L>>3)&3); frag reads use
// slot g^((rin>>1)&3) -> 2-way max bank aliasing (free).
// ---------------------------------------------------------------------------
__global__ __launch_bounds__(256, 2) void mfma_gemm(
    const u16* __restrict__ Ah, const u16* __restrict__ Al,
    const u16* __restrict__ Wh, const u16* __restrict__ Wl,
    const float* __restrict__ b0, const float* __restrict__ b1, const float* __restrict__ b2,
    void* __restrict__ C0, void* __restrict__ C1, void* __restrict__ C2,
    int nseg, int out_bf16)
{
    const int tid = threadIdx.x;
    const int w   = tid >> 6;
    const int L   = tid & 63;
    const int wr  = w >> 1, wc = w & 1;
    const int mBase = blockIdx.x * 128;
    const int nBase = blockIdx.y * 128;
    const int sel  = nBase / 768;
    const int nOff = nBase % 768;

    __shared__ __align__(16) u16 As[128 * 32];
    __shared__ __align__(16) u16 Bs[128 * 32];

    f32x4 acc[4][4];
    #pragma unroll
    for (int i = 0; i < 4; ++i)
        #pragma unroll
        for (int j = 0; j < 4; ++j)
            acc[i][j] = (f32x4){0.f, 0.f, 0.f, 0.f};

    const int srow = L >> 2;                         // row within 16-row chunk
    const int scol = ((L & 3) ^ ((L >> 3) & 3)) * 8; // swizzled k-group

    for (int seg = 0; seg < nseg; ++seg) {
        const u16* Aseg = (seg == 2) ? Al : Ah;
        const u16* Wseg = (seg == 1) ? Wl : Wh;
        for (int kb = 0; kb < 768; kb += 32) {
            #pragma unroll
            for (int i = 0; i < 2; ++i) {
                const int ch = w * 2 + i;
                const int rA = mBase + ch * 16 + srow;
                async_load16(&Aseg[(size_t)rA * 768 + kb + scol], &As[ch * 512]);
                const int rB = nBase + ch * 16 + srow;
                async_load16(&Wseg[(size_t)rB * 768 + kb + scol], &Bs[ch * 512]);
            }
            __syncthreads();
            const int rin = L & 15, g = L >> 4;
            const int sw  = (g ^ ((rin >> 1) & 3)) * 8;
            bf16x8 af[4], bfr[4];
            #pragma unroll
            for (int i = 0; i < 4; ++i)
                af[i] = *(const bf16x8*)&As[(wr * 64 + i * 16 + rin) * 32 + sw];
            #pragma unroll
            for (int j = 0; j < 4; ++j)
                bfr[j] = *(const bf16x8*)&Bs[(wc * 64 + j * 16 + rin) * 32 + sw];
            #pragma unroll
            for (int i = 0; i < 4; ++i)
                #pragma unroll
                for (int j = 0; j < 4; ++j)
                    acc[i][j] = __builtin_amdgcn_mfma_f32_16x16x32_bf16(af[i], bfr[j], acc[i][j], 0, 0, 0);
            __syncthreads();
        }
    }

    const float* bsel = (sel == 0) ? b0 : ((sel == 1) ? b1 : b2);
    void* Csel = (sel == 0) ? C0 : ((sel == 1) ? C1 : C2);
    const int rin = L & 15, rq = (L >> 4) * 4;

    #pragma unroll
    for (int j = 0; j < 4; ++j) {
        const int c = nOff + wc * 64 + j * 16 + rin;
        const float bv = bsel[c];
        #pragma unroll
        for (int i = 0; i < 4; ++i) {
            const int r0 = mBase + wr * 64 + i * 16 + rq;
            #pragma unroll
            for (int reg = 0; reg < 4; ++reg) {
                const float v = acc[i][j][reg] + bv;
                if (out_bf16) ((u16*)Csel)[(size_t)(r0 + reg) * 768 + c] = f2bf(v);
                else          ((float*)Csel)[(size_t)(r0 + reg) * 768 + c] = v;
            }
        }
    }
}

// ---------------------------------------------------------------------------
// Phase A: per (b,h) pair, partial M = K_h^T V_h over a 256-row t-chunk. fp32.
// ---------------------------------------------------------------------------
__global__ __launch_bounds__(256, 1) void kv_outer(
    const float* __restrict__ Kbuf, const float* __restrict__ Vbuf,
    float* __restrict__ Mpart)
{
    const int chunk = blockIdx.x;
    const int p     = blockIdx.y;
    const int b = p / NHEAD, h = p % NHEAD;
    const float* Kb = Kbuf + (size_t)b * PER_BATCH + (size_t)h * PER_HEAD + (size_t)chunk * 256 * DKH;
    const float* Vb = Vbuf + (size_t)b * PER_BATCH + (size_t)h * PER_HEAD + (size_t)chunk * 256 * DKH;

    __shared__ __align__(16) float Ks[32][64];
    __shared__ __align__(16) float Vs[32][64];

    const int tid = threadIdx.x;
    const int tx  = tid & 15;
    const int ty  = tid >> 4;

    float acc[4][4];
    #pragma unroll
    for (int i = 0; i < 4; ++i)
        #pragma unroll
        for (int j = 0; j < 4; ++j) acc[i][j] = 0.f;

    for (int t0 = 0; t0 < 256; t0 += 32) {
        #pragma unroll
        for (int r = 0; r < 2; ++r) {
            int idx = tid + 256 * r;
            int row = idx >> 4;
            int c4  = idx & 15;
            *(float4*)&Ks[row][c4 * 4] = *(const float4*)&Kb[(size_t)(t0 + row) * DKH + c4 * 4];
            *(float4*)&Vs[row][c4 * 4] = *(const float4*)&Vb[(size_t)(t0 + row) * DKH + c4 * 4];
        }
        __syncthreads();
        #pragma unroll
        for (int tt = 0; tt < 32; ++tt) {
            float4 ka = *(const float4*)&Ks[tt][ty * 4];
            float4 va = *(const float4*)&Vs[tt][tx * 4];
            float a[4] = {ka.x, ka.y, ka.z, ka.w};
            float v[4] = {va.x, va.y, va.z, va.w};
            #pragma unroll
            for (int i = 0; i < 4; ++i)
                #pragma unroll
                for (int j = 0; j < 4; ++j)
                    acc[i][j] += a[i] * v[j];
        }
        __syncthreads();
    }

    float* Mo = Mpart + ((size_t)p * 8 + chunk) * 4096;
    #pragma unroll
    for (int i = 0; i < 4; ++i)
        #pragma unroll
        for (int j = 0; j < 4; ++j)
            Mo[(ty * 4 + i) * 64 + tx * 4 + j] = acc[i][j];
}

// ---------------------------------------------------------------------------
// Reduce the 8 chunk-partials of M once per pair, pre-scaled. 24 blocks.
// ---------------------------------------------------------------------------
__global__ __launch_bounds__(256, 1) void reduce_M(
    const float* __restrict__ Mpart, float* __restrict__ Mred)
{
    const int p = blockIdx.x;
    const float4* Mp4 = (const float4*)Mpart + (size_t)p * 8192;
    float4* Mr4 = (float4*)Mred + (size_t)p * 1024;
    #pragma unroll
    for (int r = 0; r < 4; ++r) {
        int e4 = threadIdx.x + 256 * r;
        float4 s = Mp4[e4];
        #pragma unroll
        for (int c = 1; c < 8; ++c) {
            float4 t = Mp4[(size_t)c * 1024 + e4];
            s.x += t.x; s.y += t.y; s.z += t.z; s.w += t.w;
        }
        s.x *= ATT_SCALE; s.y *= ATT_SCALE; s.z *= ATT_SCALE; s.w *= ATT_SCALE;
        Mr4[e4] = s;
    }
}

// ---------------------------------------------------------------------------
// Phase B: register-tiled T = Q@Mred + fused softmax (64x64 tile, one barrier).
// ---------------------------------------------------------------------------
__global__ __launch_bounds__(256, 2) void attn_gemm(
    const float* __restrict__ Qbuf, const float* __restrict__ Mred,
    u16* __restrict__ MH)
{
    const int chunk = blockIdx.x;   // 0..31
    const int p     = blockIdx.y;   // 0..23
    const int b = p / NHEAD, h = p % NHEAD;
    const float* Qb = Qbuf + (size_t)b * PER_BATCH + (size_t)h * PER_HEAD + (size_t)chunk * 64 * DKH;
    u16* MHb        = MH   + (size_t)b * PER_BATCH + (size_t)h * PER_HEAD + (size_t)chunk * 64 * DKH;

    __shared__ float QsT[64][65];
    __shared__ __align__(16) float SM[64][64];

    const int tid = threadIdx.x;

    const float4* M4 = (const float4*)(Mred + (size_t)p * 4096);
    float4* SM4 = (float4*)SM;
    #pragma unroll
    for (int r = 0; r < 4; ++r) {
        int e4 = tid + 256 * r;
        SM4[e4] = M4[e4];
        int row = e4 >> 4, c4 = e4 & 15;
        float4 v = *(const float4*)&Qb[(size_t)row * DKH + c4 * 4];
        QsT[c4 * 4 + 0][row] = v.x; QsT[c4 * 4 + 1][row] = v.y;
        QsT[c4 * 4 + 2][row] = v.z; QsT[c4 * 4 + 3][row] = v.w;
    }
    __syncthreads();

    const int tx = tid & 15;
    const int ty = tid >> 4;

    float acc[4][4];
    #pragma unroll
    for (int i = 0; i < 4; ++i)
        #pragma unroll
        for (int j = 0; j < 4; ++j) acc[i][j] = 0.f;

    #pragma unroll 4
    for (int k = 0; k < 64; ++k) {
        float4 bv = *(const float4*)&SM[k][tx * 4];
        float aa[4] = {QsT[k][ty * 4 + 0], QsT[k][ty * 4 + 1],
                       QsT[k][ty * 4 + 2], QsT[k][ty * 4 + 3]};
        float bb[4] = {bv.x, bv.y, bv.z, bv.w};
        #pragma unroll
        for (int i = 0; i < 4; ++i)
            #pragma unroll
            for (int j = 0; j < 4; ++j)
                acc[i][j] += aa[i] * bb[j];
    }

    #pragma unroll
    for (int i = 0; i < 4; ++i) {
        float m = fmaxf(fmaxf(acc[i][0], acc[i][1]), fmaxf(acc[i][2], acc[i][3]));
        #pragma unroll
        for (int off = 1; off < 16; off <<= 1)
            m = fmaxf(m, __shfl_xor(m, off, 64));
        float e0 = __expf(acc[i][0] - m), e1 = __expf(acc[i][1] - m);
        float e2 = __expf(acc[i][2] - m), e3 = __expf(acc[i][3] - m);
        float s = (e0 + e1) + (e2 + e3);
        #pragma unroll
        for (int off = 1; off < 16; off <<= 1)
            s += __shfl_xor(s, off, 64);
        float inv = 1.f / s;
        u16 o0 = f2bf(e0 * inv), o1 = f2bf(e1 * inv);
        u16 o2 = f2bf(e2 * inv), o3 = f2bf(e3 * inv);
        uint2 pk; pk.x = (u32)o0 | ((u32)o1 << 16); pk.y = (u32)o2 | ((u32)o3 << 16);
        const int row = ty * 4 + i;
        *(uint2*)&MHb[(size_t)row * DKH + tx * 4] = pk;
    }
}

// ---------------------------------------------------------------------------
extern "C" void kernel_launch(void* const* d_in, const int* in_sizes, int n_in,
                              void* d_out, int out_size, void* d_ws, size_t ws_size,
                              hipStream_t stream)
{
    const float* x  = (const float*)d_in[0];
    const float* Wq = (const float*)d_in[1];
    const float* bq = (const float*)d_in[2];
    const float* Wk = (const float*)d_in[3];
    const float* bk = (const float*)d_in[4];
    const float* Wv = (const float*)d_in[5];
    const float* bv = (const float*)d_in[6];
    const float* Wo = (const float*)d_in[7];
    const float* bo = (const float*)d_in[8];
    const float* Wf = (const float*)d_in[9];
    const float* bf = (const float*)d_in[10];
    float* out = (float*)d_out;

    // Workspace (floats):
    //   Q(3.1M) K(3.1M) V(3.1M) Mpart(0.79M) Mred(98K)
    //   u16 region: xh(3.1M) xl(3.1M) Wh3(1.77M) Wl3(1.77M) Wfh(0.59M)
    // Aliases (dead-after-kv_outer regions): WoT->K, Wcb/bc/zeros->V; MH->xh.
    float* ws_f = (float*)d_ws;
    float* Q   = ws_f;
    float* Kb  = ws_f + 3145728;
    float* Vb  = ws_f + 6291456;
    float* Mp  = ws_f + 9437184;
    float* Mrd = ws_f + 10223616;
    u16* ub  = (u16*)(ws_f + 10321920);
    u16* xh  = ub;
    u16* xl  = ub + 3145728;
    u16* Wh3 = ub + 6291456;
    u16* Wl3 = Wh3 + 1769472;
    u16* Wfh = Wl3 + 1769472;
    u16* MH  = xh;

    u16*   WoT   = (u16*)Kb;            // 589824 u16, alive after kv_outer
    u16*   Wcb   = (u16*)Vb;            // 589824 u16 (294912 floats)
    float* bc    = Vb + 300032;         // 768 floats
    float* zeros = Vb + 301056;         // 768 floats

    dim3 blk(256);
    conv_all<<<dim3(128, 5), blk, 0, stream>>>(x, Wq, Wk, Wv, Wf, xh, xl, Wh3, Wl3, Wfh);
    // QKV: bf16x2-split MFMA GEMM (3 segments), fp32 out
    mfma_gemm<<<dim3(32, 18), blk, 0, stream>>>(xh, xl, Wh3, Wl3, bq, bk, bv, Q, Kb, Vb, 3, 0);
    // Attention core (fp32)
    kv_outer<<<dim3(8, 24), blk, 0, stream>>>(Kb, Vb, Mp);
    reduce_M<<<dim3(24), blk, 0, stream>>>(Mp, Mrd);
    // Fused-projection prep: WoT, bc/zeros, Wc = Wf@Wo (bf16 MFMA)
    transpose_wo<<<dim3(24, 24), blk, 0, stream>>>(Wo, WoT);
    bc_kernel<<<dim3(192), blk, 0, stream>>>(Wf, bo, bf, bc, zeros);
    mfma_gemm<<<dim3(6, 6), blk, 0, stream>>>(Wfh, nullptr, WoT, nullptr, zeros, zeros, zeros,
                                              Wcb, Wcb, Wcb, 1, 1);
    // Softmax rows -> MH (bf16)
    attn_gemm<<<dim3(32, 24), blk, 0, stream>>>(Q, Mrd, MH);
    // Single fused output projection: out = MH @ Wc^T + bc (fp32 out)
    mfma_gemm<<<dim3(32, 6), blk, 0, stream>>>(MH, nullptr, Wcb, nullptr, bc, bc, bc,
                                               out, out, out, 1, 0);
}

// Round 5
// 189.390 us; speedup vs baseline: 3.2222x; 1.1707x over previous
//
#include <hip/hip_runtime.h>
#include <math.h>

typedef unsigned short u16;
typedef unsigned int   u32;
typedef __attribute__((ext_vector_type(8))) short bf16x8;
typedef __attribute__((ext_vector_type(4))) float f32x4;

#define DMODEL 768
#define SEQ    2048
#define BATCH  2
#define NHEAD  12
#define DKH    64
#define PER_BATCH (SEQ*DMODEL)
#define PER_HEAD  (SEQ*DKH)
#define ATT_SCALE 0.125f

__device__ inline u16 f2bf(float f) {
    u32 u = __float_as_uint(f);
    u32 r = (u + 0x7FFFu + ((u >> 16) & 1u)) >> 16;
    return (u16)r;
}
__device__ inline float bf2f(u16 h) { return __uint_as_float(((u32)h) << 16); }

__device__ inline void async_load16(const void* g, void* l) {
    __builtin_amdgcn_global_load_lds(
        (const __attribute__((address_space(1))) unsigned int*)g,
        (__attribute__((address_space(3))) unsigned int*)l, 16, 0, 0);
}

// ---------------------------------------------------------------------------
// Conversion: z=0 split x -> xh,xl ; z=1..3 split Wq/Wk/Wv -> stacked Wh3,Wl3 ;
// z=4 cast Wf -> Wfh ; z=5 bc = Wf@bo + bf.
// ---------------------------------------------------------------------------
__global__ void conv_all(const float* __restrict__ x,
                         const float* __restrict__ Wq, const float* __restrict__ Wk,
                         const float* __restrict__ Wv, const float* __restrict__ Wf,
                         const float* __restrict__ bo, const float* __restrict__ bfb,
                         u16* xh, u16* xl, u16* Wh3, u16* Wl3, u16* Wfh,
                         float* bc)
{
    const int z = blockIdx.y;
    if (z == 5) {
        // bc: 768 rows, 16 lanes per row, 48 blocks of 16 rows.
        if (blockIdx.x >= 48) return;
        const int row    = blockIdx.x * 16 + (threadIdx.x >> 4);
        const int lane16 = threadIdx.x & 15;
        const float* r = Wf + (size_t)row * 768;
        float s = 0.f;
        #pragma unroll
        for (int t = 0; t < 48; ++t) s += r[lane16 + 16 * t] * bo[lane16 + 16 * t];
        #pragma unroll
        for (int off = 8; off > 0; off >>= 1) s += __shfl_xor(s, off, 64);
        if (lane16 == 0) bc[row] = s + bfb[row];
        return;
    }
    const float* src; u16* hi; u16* lo; int n;
    switch (z) {
        case 0: src = x;  hi = xh;            lo = xl;            n = 3145728; break;
        case 1: src = Wq; hi = Wh3;           lo = Wl3;           n = 589824;  break;
        case 2: src = Wk; hi = Wh3 + 589824;  lo = Wl3 + 589824;  n = 589824;  break;
        case 3: src = Wv; hi = Wh3 + 1179648; lo = Wl3 + 1179648; n = 589824;  break;
        default:src = Wf; hi = Wfh;           lo = nullptr;       n = 589824;  break;
    }
    const int n4 = n >> 2;
    for (int i = blockIdx.x * blockDim.x + threadIdx.x; i < n4; i += gridDim.x * blockDim.x) {
        float4 v = ((const float4*)src)[i];
        u16 h0 = f2bf(v.x), h1 = f2bf(v.y), h2 = f2bf(v.z), h3 = f2bf(v.w);
        uint2 hp; hp.x = (u32)h0 | ((u32)h1 << 16); hp.y = (u32)h2 | ((u32)h3 << 16);
        ((uint2*)hi)[i] = hp;
        if (lo) {
            u16 l0 = f2bf(v.x - bf2f(h0)), l1 = f2bf(v.y - bf2f(h1));
            u16 l2 = f2bf(v.z - bf2f(h2)), l3 = f2bf(v.w - bf2f(h3));
            uint2 lp; lp.x = (u32)l0 | ((u32)l1 << 16); lp.y = (u32)l2 | ((u32)l3 << 16);
            ((uint2*)lo)[i] = lp;
        }
    }
}

// ---------------------------------------------------------------------------
// 32x32-tile LDS transpose: WoT[j,k] = bf16(Wo[k,j]).
// ---------------------------------------------------------------------------
__global__ __launch_bounds__(256, 2) void transpose_wo(
    const float* __restrict__ Wo, u16* __restrict__ WoT)
{
    __shared__ u16 S[32][33];
    const int bi = blockIdx.x, bj = blockIdx.y;
    const int r  = threadIdx.x >> 3;
    const int c4 = threadIdx.x & 7;
    float4 v = *(const float4*)&Wo[(size_t)(bi * 32 + r) * 768 + bj * 32 + c4 * 4];
    S[c4 * 4 + 0][r] = f2bf(v.x); S[c4 * 4 + 1][r] = f2bf(v.y);
    S[c4 * 4 + 2][r] = f2bf(v.z); S[c4 * 4 + 3][r] = f2bf(v.w);
    __syncthreads();
    u16 o0 = S[r][c4 * 4 + 0], o1 = S[r][c4 * 4 + 1];
    u16 o2 = S[r][c4 * 4 + 2], o3 = S[r][c4 * 4 + 3];
    uint2 pk; pk.x = (u32)o0 | ((u32)o1 << 16); pk.y = (u32)o2 | ((u32)o3 << 16);
    *(uint2*)&WoT[(size_t)(bj * 32 + r) * 768 + bi * 32 + c4 * 4] = pk;
}

// ---------------------------------------------------------------------------
// Fused-split QKV GEMM: C = (Ah+Al) @ (Wh+Wl)^T + bias ~= AhWh + AhWl + AlWh.
// Tile 64x128, BK=64, 256 thr (4 waves 2x2, each 32x64 = 2x4 16x16x32 frags).
// All four operand tiles staged at once (48 KB LDS, single buffer); 48 MFMA
// per wave per barrier-pair; 12 barrier-pairs total (K=768).
// LDS XOR-swizzle: lane (srow=L>>3, g=L&7) fetches k-group g^(srow&7); reads
// use slot (kq*4+q)^(rin&7) -> 2-way max (free).
// ---------------------------------------------------------------------------
__global__ __launch_bounds__(256, 3) void qkv_gemm(
    const u16* __restrict__ Ah, const u16* __restrict__ Al,
    const u16* __restrict__ Wh, const u16* __restrict__ Wl,
    const float* __restrict__ b0, const float* __restrict__ b1, const float* __restrict__ b2,
    float* __restrict__ C0, float* __restrict__ C1, float* __restrict__ C2)
{
    const int tid = threadIdx.x;
    const int w   = tid >> 6;
    const int L   = tid & 63;
    const int wr  = w >> 1, wc = w & 1;
    const int mBase = blockIdx.x * 64;
    const int nBase = blockIdx.y * 128;
    const int sel  = nBase / 768;
    const int nOff = nBase % 768;

    __shared__ __align__(16) u16 AsH[64 * 64];
    __shared__ __align__(16) u16 AsL[64 * 64];
    __shared__ __align__(16) u16 BsH[128 * 64];
    __shared__ __align__(16) u16 BsL[128 * 64];

    f32x4 acc[2][4];
    #pragma unroll
    for (int i = 0; i < 2; ++i)
        #pragma unroll
        for (int j = 0; j < 4; ++j)
            acc[i][j] = (f32x4){0.f, 0.f, 0.f, 0.f};

    const int srow = L >> 3;                       // 0..7
    const int kScr = ((L & 7) ^ (srow & 7)) * 8;   // swizzled k-element offset
    const int rin = L & 15, q = L >> 4;

    for (int kb = 0; kb < 768; kb += 64) {
        if (kb) __syncthreads();
        // A chunks: wave w stages chunk w (16 rows, 2 asyncs per matrix).
        {
            const size_t rA = (size_t)(mBase + w * 16 + srow) * 768 + kb + kScr;
            async_load16(&Ah[rA],           &AsH[w * 1024]);
            async_load16(&Ah[rA + 8 * 768], &AsH[w * 1024 + 512]);
            async_load16(&Al[rA],           &AsL[w * 1024]);
            async_load16(&Al[rA + 8 * 768], &AsL[w * 1024 + 512]);
        }
        // B chunks: wave w stages chunks 2w, 2w+1.
        #pragma unroll
        for (int cc = 0; cc < 2; ++cc) {
            const int cB = w * 2 + cc;
            const size_t rB = (size_t)(nBase + cB * 16 + srow) * 768 + kb + kScr;
            async_load16(&Wh[rB],           &BsH[cB * 1024]);
            async_load16(&Wh[rB + 8 * 768], &BsH[cB * 1024 + 512]);
            async_load16(&Wl[rB],           &BsL[cB * 1024]);
            async_load16(&Wl[rB + 8 * 768], &BsL[cB * 1024 + 512]);
        }
        __syncthreads();

        #pragma unroll
        for (int kq = 0; kq < 2; ++kq) {
            const int slot = ((kq * 4 + q) ^ (rin & 7)) * 8;
            bf16x8 ah[2], al[2], bh[4], bl[4];
            #pragma unroll
            for (int i = 0; i < 2; ++i) {
                ah[i] = *(const bf16x8*)&AsH[(wr * 2 + i) * 1024 + rin * 64 + slot];
                al[i] = *(const bf16x8*)&AsL[(wr * 2 + i) * 1024 + rin * 64 + slot];
            }
            #pragma unroll
            for (int j = 0; j < 4; ++j) {
                bh[j] = *(const bf16x8*)&BsH[(wc * 4 + j) * 1024 + rin * 64 + slot];
                bl[j] = *(const bf16x8*)&BsL[(wc * 4 + j) * 1024 + rin * 64 + slot];
            }
            #pragma unroll
            for (int i = 0; i < 2; ++i)
                #pragma unroll
                for (int j = 0; j < 4; ++j) {
                    acc[i][j] = __builtin_amdgcn_mfma_f32_16x16x32_bf16(ah[i], bh[j], acc[i][j], 0, 0, 0);
                    acc[i][j] = __builtin_amdgcn_mfma_f32_16x16x32_bf16(ah[i], bl[j], acc[i][j], 0, 0, 0);
                    acc[i][j] = __builtin_amdgcn_mfma_f32_16x16x32_bf16(al[i], bh[j], acc[i][j], 0, 0, 0);
                }
        }
    }

    const float* bsel = (sel == 0) ? b0 : ((sel == 1) ? b1 : b2);
    float* Csel = (sel == 0) ? C0 : ((sel == 1) ? C1 : C2);

    #pragma unroll
    for (int j = 0; j < 4; ++j) {
        const int c = nOff + wc * 64 + j * 16 + rin;
        const float bv = bsel[c];
        #pragma unroll
        for (int i = 0; i < 2; ++i) {
            const int r0 = mBase + wr * 32 + i * 16 + q * 4;
            #pragma unroll
            for (int reg = 0; reg < 4; ++reg)
                Csel[(size_t)(r0 + reg) * 768 + c] = acc[i][j][reg] + bv;
        }
    }
}

// ---------------------------------------------------------------------------
// Plain bf16 MFMA GEMM: C = A @ B^T + bias.  A: Mx768, B: Nx768 (both bf16).
// Tile 64x128, BK=64, same structure as qkv_gemm minus the low parts.
// ---------------------------------------------------------------------------
__global__ __launch_bounds__(256, 4) void gemm_bf16(
    const u16* __restrict__ A, const u16* __restrict__ B,
    const float* __restrict__ bias, void* __restrict__ C, int out_bf16)
{
    const int tid = threadIdx.x;
    const int w   = tid >> 6;
    const int L   = tid & 63;
    const int wr  = w >> 1, wc = w & 1;
    const int mBase = blockIdx.x * 64;
    const int nBase = blockIdx.y * 128;

    __shared__ __align__(16) u16 As[64 * 64];
    __shared__ __align__(16) u16 Bs[128 * 64];

    f32x4 acc[2][4];
    #pragma unroll
    for (int i = 0; i < 2; ++i)
        #pragma unroll
        for (int j = 0; j < 4; ++j)
            acc[i][j] = (f32x4){0.f, 0.f, 0.f, 0.f};

    const int srow = L >> 3;
    const int kScr = ((L & 7) ^ (srow & 7)) * 8;
    const int rin = L & 15, q = L >> 4;

    for (int kb = 0; kb < 768; kb += 64) {
        if (kb) __syncthreads();
        {
            const size_t rA = (size_t)(mBase + w * 16 + srow) * 768 + kb + kScr;
            async_load16(&A[rA],           &As[w * 1024]);
            async_load16(&A[rA + 8 * 768], &As[w * 1024 + 512]);
        }
        #pragma unroll
        for (int cc = 0; cc < 2; ++cc) {
            const int cB = w * 2 + cc;
            const size_t rB = (size_t)(nBase + cB * 16 + srow) * 768 + kb + kScr;
            async_load16(&B[rB],           &Bs[cB * 1024]);
            async_load16(&B[rB + 8 * 768], &Bs[cB * 1024 + 512]);
        }
        __syncthreads();

        #pragma unroll
        for (int kq = 0; kq < 2; ++kq) {
            const int slot = ((kq * 4 + q) ^ (rin & 7)) * 8;
            bf16x8 af[2], bfr[4];
            #pragma unroll
            for (int i = 0; i < 2; ++i)
                af[i] = *(const bf16x8*)&As[(wr * 2 + i) * 1024 + rin * 64 + slot];
            #pragma unroll
            for (int j = 0; j < 4; ++j)
                bfr[j] = *(const bf16x8*)&Bs[(wc * 4 + j) * 1024 + rin * 64 + slot];
            #pragma unroll
            for (int i = 0; i < 2; ++i)
                #pragma unroll
                for (int j = 0; j < 4; ++j)
                    acc[i][j] = __builtin_amdgcn_mfma_f32_16x16x32_bf16(af[i], bfr[j], acc[i][j], 0, 0, 0);
        }
    }

    #pragma unroll
    for (int j = 0; j < 4; ++j) {
        const int c = nBase + wc * 64 + j * 16 + rin;
        const float bv = bias ? bias[c] : 0.f;
        #pragma unroll
        for (int i = 0; i < 2; ++i) {
            const int r0 = mBase + wr * 32 + i * 16 + q * 4;
            #pragma unroll
            for (int reg = 0; reg < 4; ++reg) {
                const float v = acc[i][j][reg] + bv;
                if (out_bf16) ((u16*)C)[(size_t)(r0 + reg) * 768 + c] = f2bf(v);
                else          ((float*)C)[(size_t)(r0 + reg) * 768 + c] = v;
            }
        }
    }
}

// ---------------------------------------------------------------------------
// Phase A: per (b,h) pair, partial M = K_h^T V_h over a 128-row t-chunk. fp32.
// grid (16, 24) = 384 blocks.
// ---------------------------------------------------------------------------
__global__ __launch_bounds__(256, 1) void kv_outer(
    const float* __restrict__ Kbuf, const float* __restrict__ Vbuf,
    float* __restrict__ Mpart)
{
    const int chunk = blockIdx.x;   // 0..15
    const int p     = blockIdx.y;   // 0..23
    const int b = p / NHEAD, h = p % NHEAD;
    const float* Kb = Kbuf + (size_t)b * PER_BATCH + (size_t)h * PER_HEAD + (size_t)chunk * 128 * DKH;
    const float* Vb = Vbuf + (size_t)b * PER_BATCH + (size_t)h * PER_HEAD + (size_t)chunk * 128 * DKH;

    __shared__ __align__(16) float Ks[32][64];
    __shared__ __align__(16) float Vs[32][64];

    const int tid = threadIdx.x;
    const int tx  = tid & 15;
    const int ty  = tid >> 4;

    float acc[4][4];
    #pragma unroll
    for (int i = 0; i < 4; ++i)
        #pragma unroll
        for (int j = 0; j < 4; ++j) acc[i][j] = 0.f;

    for (int t0 = 0; t0 < 128; t0 += 32) {
        #pragma unroll
        for (int r = 0; r < 2; ++r) {
            int idx = tid + 256 * r;
            int row = idx >> 4;
            int c4  = idx & 15;
            *(float4*)&Ks[row][c4 * 4] = *(const float4*)&Kb[(size_t)(t0 + row) * DKH + c4 * 4];
            *(float4*)&Vs[row][c4 * 4] = *(const float4*)&Vb[(size_t)(t0 + row) * DKH + c4 * 4];
        }
        __syncthreads();
        #pragma unroll
        for (int tt = 0; tt < 32; ++tt) {
            float4 ka = *(const float4*)&Ks[tt][ty * 4];
            float4 va = *(const float4*)&Vs[tt][tx * 4];
            float a[4] = {ka.x, ka.y, ka.z, ka.w};
            float v[4] = {va.x, va.y, va.z, va.w};
            #pragma unroll
            for (int i = 0; i < 4; ++i)
                #pragma unroll
                for (int j = 0; j < 4; ++j)
                    acc[i][j] += a[i] * v[j];
        }
        __syncthreads();
    }

    float* Mo = Mpart + ((size_t)p * 16 + chunk) * 4096;
    #pragma unroll
    for (int i = 0; i < 4; ++i)
        #pragma unroll
        for (int j = 0; j < 4; ++j)
            Mo[(ty * 4 + i) * 64 + tx * 4 + j] = acc[i][j];
}

// ---------------------------------------------------------------------------
// Reduce the 16 chunk-partials of M, pre-scaled. grid (24, 4).
// ---------------------------------------------------------------------------
__global__ __launch_bounds__(256, 2) void reduce_M(
    const float* __restrict__ Mpart, float* __restrict__ Mred)
{
    const int p = blockIdx.x;
    const int e4 = blockIdx.y * 256 + threadIdx.x;   // 0..1023
    const float4* Mp4 = (const float4*)Mpart + (size_t)p * 16384;
    float4 s = Mp4[e4];
    #pragma unroll
    for (int c = 1; c < 16; ++c) {
        float4 t = Mp4[(size_t)c * 1024 + e4];
        s.x += t.x; s.y += t.y; s.z += t.z; s.w += t.w;
    }
    s.x *= ATT_SCALE; s.y *= ATT_SCALE; s.z *= ATT_SCALE; s.w *= ATT_SCALE;
    ((float4*)Mred)[(size_t)p * 1024 + e4] = s;
}

// ---------------------------------------------------------------------------
// Phase B: register-tiled T = Q@Mred + fused softmax (64x64 tile, one barrier).
// ---------------------------------------------------------------------------
__global__ __launch_bounds__(256, 2) void attn_gemm(
    const float* __restrict__ Qbuf, const float* __restrict__ Mred,
    u16* __restrict__ MH)
{
    const int chunk = blockIdx.x;   // 0..31
    const int p     = blockIdx.y;   // 0..23
    const int b = p / NHEAD, h = p % NHEAD;
    const float* Qb = Qbuf + (size_t)b * PER_BATCH + (size_t)h * PER_HEAD + (size_t)chunk * 64 * DKH;
    u16* MHb        = MH   + (size_t)b * PER_BATCH + (size_t)h * PER_HEAD + (size_t)chunk * 64 * DKH;

    __shared__ float QsT[64][65];
    __shared__ __align__(16) float SM[64][64];

    const int tid = threadIdx.x;

    const float4* M4 = (const float4*)(Mred + (size_t)p * 4096);
    float4* SM4 = (float4*)SM;
    #pragma unroll
    for (int r = 0; r < 4; ++r) {
        int e4 = tid + 256 * r;
        SM4[e4] = M4[e4];
        int row = e4 >> 4, c4 = e4 & 15;
        float4 v = *(const float4*)&Qb[(size_t)row * DKH + c4 * 4];
        QsT[c4 * 4 + 0][row] = v.x; QsT[c4 * 4 + 1][row] = v.y;
        QsT[c4 * 4 + 2][row] = v.z; QsT[c4 * 4 + 3][row] = v.w;
    }
    __syncthreads();

    const int tx = tid & 15;
    const int ty = tid >> 4;

    float acc[4][4];
    #pragma unroll
    for (int i = 0; i < 4; ++i)
        #pragma unroll
        for (int j = 0; j < 4; ++j) acc[i][j] = 0.f;

    #pragma unroll 4
    for (int k = 0; k < 64; ++k) {
        float4 bv = *(const float4*)&SM[k][tx * 4];
        float aa[4] = {QsT[k][ty * 4 + 0], QsT[k][ty * 4 + 1],
                       QsT[k][ty * 4 + 2], QsT[k][ty * 4 + 3]};
        float bb[4] = {bv.x, bv.y, bv.z, bv.w};
        #pragma unroll
        for (int i = 0; i < 4; ++i)
            #pragma unroll
            for (int j = 0; j < 4; ++j)
                acc[i][j] += aa[i] * bb[j];
    }

    #pragma unroll
    for (int i = 0; i < 4; ++i) {
        float m = fmaxf(fmaxf(acc[i][0], acc[i][1]), fmaxf(acc[i][2], acc[i][3]));
        #pragma unroll
        for (int off = 1; off < 16; off <<= 1)
            m = fmaxf(m, __shfl_xor(m, off, 64));
        float e0 = __expf(acc[i][0] - m), e1 = __expf(acc[i][1] - m);
        float e2 = __expf(acc[i][2] - m), e3 = __expf(acc[i][3] - m);
        float s = (e0 + e1) + (e2 + e3);
        #pragma unroll
        for (int off = 1; off < 16; off <<= 1)
            s += __shfl_xor(s, off, 64);
        float inv = 1.f / s;
        u16 o0 = f2bf(e0 * inv), o1 = f2bf(e1 * inv);
        u16 o2 = f2bf(e2 * inv), o3 = f2bf(e3 * inv);
        uint2 pk; pk.x = (u32)o0 | ((u32)o1 << 16); pk.y = (u32)o2 | ((u32)o3 << 16);
        const int row = ty * 4 + i;
        *(uint2*)&MHb[(size_t)row * DKH + tx * 4] = pk;
    }
}

// ---------------------------------------------------------------------------
extern "C" void kernel_launch(void* const* d_in, const int* in_sizes, int n_in,
                              void* d_out, int out_size, void* d_ws, size_t ws_size,
                              hipStream_t stream)
{
    const float* x  = (const float*)d_in[0];
    const float* Wq = (const float*)d_in[1];
    const float* bq = (const float*)d_in[2];
    const float* Wk = (const float*)d_in[3];
    const float* bk = (const float*)d_in[4];
    const float* Wv = (const float*)d_in[5];
    const float* bv = (const float*)d_in[6];
    const float* Wo = (const float*)d_in[7];
    const float* bo = (const float*)d_in[8];
    const float* Wf = (const float*)d_in[9];
    const float* bf = (const float*)d_in[10];
    float* out = (float*)d_out;

    // Workspace (floats): Q(3.1M) K(3.1M) V(3.1M) Mpart(1.57M) Mred(98K) bc(768)
    // then u16: xh(3.1M) xl(3.1M) Wh3(1.77M) Wl3(1.77M) Wfh(0.59M)
    // Aliases: WoT->K, Wcb->V (dead after kv_outer); MH->xh (dead after qkv).
    float* ws_f = (float*)d_ws;
    float* Q   = ws_f;
    float* Kb  = ws_f + 3145728;
    float* Vb  = ws_f + 6291456;
    float* Mp  = ws_f + 9437184;
    float* Mrd = ws_f + 11010048;
    float* bc  = ws_f + 11108352;
    u16* ub  = (u16*)(ws_f + 11109376);
    u16* xh  = ub;
    u16* xl  = ub + 3145728;
    u16* Wh3 = ub + 6291456;
    u16* Wl3 = Wh3 + 1769472;
    u16* Wfh = Wl3 + 1769472;
    u16* MH  = xh;
    u16* WoT = (u16*)Kb;
    u16* Wcb = (u16*)Vb;

    dim3 blk(256);
    conv_all<<<dim3(256, 6), blk, 0, stream>>>(x, Wq, Wk, Wv, Wf, bo, bf,
                                               xh, xl, Wh3, Wl3, Wfh, bc);
    // QKV: fused 3-combo split GEMM, 1152 blocks
    qkv_gemm<<<dim3(64, 18), blk, 0, stream>>>(xh, xl, Wh3, Wl3, bq, bk, bv, Q, Kb, Vb);
    // Attention core (fp32)
    kv_outer<<<dim3(16, 24), blk, 0, stream>>>(Kb, Vb, Mp);
    reduce_M<<<dim3(24, 4), blk, 0, stream>>>(Mp, Mrd);
    // Fused-projection prep (K/V regions now dead)
    transpose_wo<<<dim3(24, 24), blk, 0, stream>>>(Wo, WoT);
    gemm_bf16<<<dim3(12, 6), blk, 0, stream>>>(Wfh, WoT, nullptr, Wcb, 1);
    // Softmax rows -> MH (bf16)
    attn_gemm<<<dim3(32, 24), blk, 0, stream>>>(Q, Mrd, MH);
    // Single fused output projection: out = MH @ Wc^T + bc (fp32 out)
    gemm_bf16<<<dim3(64, 6), blk, 0, stream>>>(MH, Wcb, bc, out, 0);
}

// Round 6
// 159.612 us; speedup vs baseline: 3.8233x; 1.1866x over previous
//
#include <hip/hip_runtime.h>
#include <math.h>

typedef unsigned short u16;
typedef unsigned int   u32;
typedef __attribute__((ext_vector_type(8))) _Float16 f16x8;
typedef __attribute__((ext_vector_type(4))) float f32x4;

#define DMODEL 768
#define SEQ    2048
#define BATCH  2
#define NHEAD  12
#define DKH    64
#define PER_BATCH (SEQ*DMODEL)
#define PER_HEAD  (SEQ*DKH)
#define ATT_SCALE 0.125f

__device__ inline u16 f2h(float f) {
    _Float16 h = (_Float16)f;           // v_cvt_f16_f32, RTNE
    return *(u16*)&h;
}

__device__ inline void async_load16(const void* g, void* l) {
    __builtin_amdgcn_global_load_lds(
        (const __attribute__((address_space(1))) unsigned int*)g,
        (__attribute__((address_space(3))) unsigned int*)l, 16, 0, 0);
}

// ---------------------------------------------------------------------------
// Conversion / prep, one launch. z=0: x->xh(fp16); z=1..3: Wq/Wk/Wv->Wh3;
// z=4: Wf->Wfh; z=5: bc = Wf@bo + bf; z=6: WoT = fp16(Wo^T) (32x32 tiles).
// grid (576, 7).
// ---------------------------------------------------------------------------
__global__ void conv_all(const float* __restrict__ x,
                         const float* __restrict__ Wq, const float* __restrict__ Wk,
                         const float* __restrict__ Wv, const float* __restrict__ Wf,
                         const float* __restrict__ Wo,
                         const float* __restrict__ bo, const float* __restrict__ bfb,
                         u16* xh, u16* Wh3, u16* Wfh, u16* WoT, float* bc)
{
    const int z = blockIdx.y;
    if (z == 5) {
        if (blockIdx.x >= 48) return;
        const int row    = blockIdx.x * 16 + (threadIdx.x >> 4);
        const int lane16 = threadIdx.x & 15;
        const float* r = Wf + (size_t)row * 768;
        float s = 0.f;
        #pragma unroll
        for (int t = 0; t < 48; ++t) s += r[lane16 + 16 * t] * bo[lane16 + 16 * t];
        #pragma unroll
        for (int off = 8; off > 0; off >>= 1) s += __shfl_xor(s, off, 64);
        if (lane16 == 0) bc[row] = s + bfb[row];
        return;
    }
    if (z == 6) {
        __shared__ u16 S[32][33];
        const int bi = blockIdx.x / 24, bj = blockIdx.x % 24;
        const int r  = threadIdx.x >> 3;
        const int c4 = threadIdx.x & 7;
        float4 v = *(const float4*)&Wo[(size_t)(bi * 32 + r) * 768 + bj * 32 + c4 * 4];
        S[c4 * 4 + 0][r] = f2h(v.x); S[c4 * 4 + 1][r] = f2h(v.y);
        S[c4 * 4 + 2][r] = f2h(v.z); S[c4 * 4 + 3][r] = f2h(v.w);
        __syncthreads();
        u16 o0 = S[r][c4 * 4 + 0], o1 = S[r][c4 * 4 + 1];
        u16 o2 = S[r][c4 * 4 + 2], o3 = S[r][c4 * 4 + 3];
        uint2 pk; pk.x = (u32)o0 | ((u32)o1 << 16); pk.y = (u32)o2 | ((u32)o3 << 16);
        *(uint2*)&WoT[(size_t)(bj * 32 + r) * 768 + bi * 32 + c4 * 4] = pk;
        return;
    }
    const float* src; u16* dst; int n;
    switch (z) {
        case 0: src = x;  dst = xh;            n = 3145728; break;
        case 1: src = Wq; dst = Wh3;           n = 589824;  break;
        case 2: src = Wk; dst = Wh3 + 589824;  n = 589824;  break;
        case 3: src = Wv; dst = Wh3 + 1179648; n = 589824;  break;
        default:src = Wf; dst = Wfh;           n = 589824;  break;
    }
    const int n4 = n >> 2;
    for (int i = blockIdx.x * blockDim.x + threadIdx.x; i < n4; i += gridDim.x * blockDim.x) {
        float4 v = ((const float4*)src)[i];
        u16 h0 = f2h(v.x), h1 = f2h(v.y), h2 = f2h(v.z), h3 = f2h(v.w);
        uint2 hp; hp.x = (u32)h0 | ((u32)h1 << 16); hp.y = (u32)h2 | ((u32)h3 << 16);
        ((uint2*)dst)[i] = hp;
    }
}

// ---------------------------------------------------------------------------
// QKV GEMM (fp16 single-pass): C = A @ W^T + bias, fp32 out.
// Tile 128x128, BK=64, 256 thr (4 waves 2x2, each 64x64 = 4x4 16x16x32 frags).
// 32 KB LDS; 8 async16/thread/iter; 16 ds_read + 32 MFMA per wave per iter.
// XOR swizzle: lane (srow=L>>3, g=L&7) fetches k-group g^(srow&7); reads use
// slot (kq*4+q)^(rin&7) -> conflict-free.
// ---------------------------------------------------------------------------
__global__ __launch_bounds__(256, 3) void qkv_gemm(
    const u16* __restrict__ Ah, const u16* __restrict__ Wh,
    const float* __restrict__ b0, const float* __restrict__ b1, const float* __restrict__ b2,
    float* __restrict__ C0, float* __restrict__ C1, float* __restrict__ C2)
{
    const int tid = threadIdx.x;
    const int w   = tid >> 6;
    const int L   = tid & 63;
    const int wr  = w >> 1, wc = w & 1;
    const int mBase = blockIdx.x * 128;
    const int nBase = blockIdx.y * 128;
    const int sel  = nBase / 768;
    const int nOff = nBase % 768;

    __shared__ __align__(16) u16 As[128 * 64];
    __shared__ __align__(16) u16 Bs[128 * 64];

    f32x4 acc[4][4];
    #pragma unroll
    for (int i = 0; i < 4; ++i)
        #pragma unroll
        for (int j = 0; j < 4; ++j)
            acc[i][j] = (f32x4){0.f, 0.f, 0.f, 0.f};

    const int srow = L >> 3;                       // 0..7
    const int kScr = ((L & 7) ^ (srow & 7)) * 8;   // swizzled k-element offset
    const int rin = L & 15, q = L >> 4;

    for (int kb = 0; kb < 768; kb += 64) {
        if (kb) __syncthreads();
        #pragma unroll
        for (int cc = 0; cc < 2; ++cc) {
            const int ch = w * 2 + cc;             // 16-row chunk 0..7
            const size_t rA = (size_t)(mBase + ch * 16 + srow) * 768 + kb + kScr;
            async_load16(&Ah[rA],           &As[ch * 1024]);
            async_load16(&Ah[rA + 8 * 768], &As[ch * 1024 + 512]);
            const size_t rB = (size_t)(nBase + ch * 16 + srow) * 768 + kb + kScr;
            async_load16(&Wh[rB],           &Bs[ch * 1024]);
            async_load16(&Wh[rB + 8 * 768], &Bs[ch * 1024 + 512]);
        }
        __syncthreads();

        #pragma unroll
        for (int kq = 0; kq < 2; ++kq) {
            const int slot = ((kq * 4 + q) ^ (rin & 7)) * 8;
            f16x8 af[4], bfr[4];
            #pragma unroll
            for (int i = 0; i < 4; ++i)
                af[i] = *(const f16x8*)&As[(wr * 64 + i * 16 + rin) * 64 + slot];
            #pragma unroll
            for (int j = 0; j < 4; ++j)
                bfr[j] = *(const f16x8*)&Bs[(wc * 64 + j * 16 + rin) * 64 + slot];
            #pragma unroll
            for (int i = 0; i < 4; ++i)
                #pragma unroll
                for (int j = 0; j < 4; ++j)
                    acc[i][j] = __builtin_amdgcn_mfma_f32_16x16x32_f16(af[i], bfr[j], acc[i][j], 0, 0, 0);
        }
    }

    const float* bsel = (sel == 0) ? b0 : ((sel == 1) ? b1 : b2);
    float* Csel = (sel == 0) ? C0 : ((sel == 1) ? C1 : C2);

    #pragma unroll
    for (int j = 0; j < 4; ++j) {
        const int c = nOff + wc * 64 + j * 16 + rin;
        const float bv = bsel[c];
        #pragma unroll
        for (int i = 0; i < 4; ++i) {
            const int r0 = mBase + wr * 64 + i * 16 + q * 4;
            #pragma unroll
            for (int reg = 0; reg < 4; ++reg)
                Csel[(size_t)(r0 + reg) * 768 + c] = acc[i][j][reg] + bv;
        }
    }
}

// ---------------------------------------------------------------------------
// Generic fp16 MFMA GEMM: C = A @ B^T + bias.  Tile 64x128, BK=64.
// ---------------------------------------------------------------------------
__global__ __launch_bounds__(256, 4) void gemm_f16(
    const u16* __restrict__ A, const u16* __restrict__ B,
    const float* __restrict__ bias, void* __restrict__ C, int out_f16)
{
    const int tid = threadIdx.x;
    const int w   = tid >> 6;
    const int L   = tid & 63;
    const int wr  = w >> 1, wc = w & 1;
    const int mBase = blockIdx.x * 64;
    const int nBase = blockIdx.y * 128;

    __shared__ __align__(16) u16 As[64 * 64];
    __shared__ __align__(16) u16 Bs[128 * 64];

    f32x4 acc[2][4];
    #pragma unroll
    for (int i = 0; i < 2; ++i)
        #pragma unroll
        for (int j = 0; j < 4; ++j)
            acc[i][j] = (f32x4){0.f, 0.f, 0.f, 0.f};

    const int srow = L >> 3;
    const int kScr = ((L & 7) ^ (srow & 7)) * 8;
    const int rin = L & 15, q = L >> 4;

    for (int kb = 0; kb < 768; kb += 64) {
        if (kb) __syncthreads();
        {
            const size_t rA = (size_t)(mBase + w * 16 + srow) * 768 + kb + kScr;
            async_load16(&A[rA],           &As[w * 1024]);
            async_load16(&A[rA + 8 * 768], &As[w * 1024 + 512]);
        }
        #pragma unroll
        for (int cc = 0; cc < 2; ++cc) {
            const int cB = w * 2 + cc;
            const size_t rB = (size_t)(nBase + cB * 16 + srow) * 768 + kb + kScr;
            async_load16(&B[rB],           &Bs[cB * 1024]);
            async_load16(&B[rB + 8 * 768], &Bs[cB * 1024 + 512]);
        }
        __syncthreads();

        #pragma unroll
        for (int kq = 0; kq < 2; ++kq) {
            const int slot = ((kq * 4 + q) ^ (rin & 7)) * 8;
            f16x8 af[2], bfr[4];
            #pragma unroll
            for (int i = 0; i < 2; ++i)
                af[i] = *(const f16x8*)&As[(wr * 2 + i) * 1024 + rin * 64 + slot];
            #pragma unroll
            for (int j = 0; j < 4; ++j)
                bfr[j] = *(const f16x8*)&Bs[(wc * 4 + j) * 1024 + rin * 64 + slot];
            #pragma unroll
            for (int i = 0; i < 2; ++i)
                #pragma unroll
                for (int j = 0; j < 4; ++j)
                    acc[i][j] = __builtin_amdgcn_mfma_f32_16x16x32_f16(af[i], bfr[j], acc[i][j], 0, 0, 0);
        }
    }

    #pragma unroll
    for (int j = 0; j < 4; ++j) {
        const int c = nBase + wc * 64 + j * 16 + rin;
        const float bv = bias ? bias[c] : 0.f;
        #pragma unroll
        for (int i = 0; i < 2; ++i) {
            const int r0 = mBase + wr * 32 + i * 16 + q * 4;
            #pragma unroll
            for (int reg = 0; reg < 4; ++reg) {
                const float v = acc[i][j][reg] + bv;
                if (out_f16) ((u16*)C)[(size_t)(r0 + reg) * 768 + c] = f2h(v);
                else         ((float*)C)[(size_t)(r0 + reg) * 768 + c] = v;
            }
        }
    }
}

// ---------------------------------------------------------------------------
// Phase A: per (b,h) pair, partial M = K_h^T V_h over a 128-row t-chunk. fp32.
// grid (16, 24).
// ---------------------------------------------------------------------------
__global__ __launch_bounds__(256, 1) void kv_outer(
    const float* __restrict__ Kbuf, const float* __restrict__ Vbuf,
    float* __restrict__ Mpart)
{
    const int chunk = blockIdx.x;
    const int p     = blockIdx.y;
    const int b = p / NHEAD, h = p % NHEAD;
    const float* Kb = Kbuf + (size_t)b * PER_BATCH + (size_t)h * PER_HEAD + (size_t)chunk * 128 * DKH;
    const float* Vb = Vbuf + (size_t)b * PER_BATCH + (size_t)h * PER_HEAD + (size_t)chunk * 128 * DKH;

    __shared__ __align__(16) float Ks[32][64];
    __shared__ __align__(16) float Vs[32][64];

    const int tid = threadIdx.x;
    const int tx  = tid & 15;
    const int ty  = tid >> 4;

    float acc[4][4];
    #pragma unroll
    for (int i = 0; i < 4; ++i)
        #pragma unroll
        for (int j = 0; j < 4; ++j) acc[i][j] = 0.f;

    for (int t0 = 0; t0 < 128; t0 += 32) {
        #pragma unroll
        for (int r = 0; r < 2; ++r) {
            int idx = tid + 256 * r;
            int row = idx >> 4;
            int c4  = idx & 15;
            *(float4*)&Ks[row][c4 * 4] = *(const float4*)&Kb[(size_t)(t0 + row) * DKH + c4 * 4];
            *(float4*)&Vs[row][c4 * 4] = *(const float4*)&Vb[(size_t)(t0 + row) * DKH + c4 * 4];
        }
        __syncthreads();
        #pragma unroll
        for (int tt = 0; tt < 32; ++tt) {
            float4 ka = *(const float4*)&Ks[tt][ty * 4];
            float4 va = *(const float4*)&Vs[tt][tx * 4];
            float a[4] = {ka.x, ka.y, ka.z, ka.w};
            float v[4] = {va.x, va.y, va.z, va.w};
            #pragma unroll
            for (int i = 0; i < 4; ++i)
                #pragma unroll
                for (int j = 0; j < 4; ++j)
                    acc[i][j] += a[i] * v[j];
        }
        __syncthreads();
    }

    float* Mo = Mpart + ((size_t)p * 16 + chunk) * 4096;
    #pragma unroll
    for (int i = 0; i < 4; ++i)
        #pragma unroll
        for (int j = 0; j < 4; ++j)
            Mo[(ty * 4 + i) * 64 + tx * 4 + j] = acc[i][j];
}

// ---------------------------------------------------------------------------
// Reduce the 16 chunk-partials of M, pre-scaled. grid (24, 4).
// ---------------------------------------------------------------------------
__global__ __launch_bounds__(256, 2) void reduce_M(
    const float* __restrict__ Mpart, float* __restrict__ Mred)
{
    const int p = blockIdx.x;
    const int e4 = blockIdx.y * 256 + threadIdx.x;
    const float4* Mp4 = (const float4*)Mpart + (size_t)p * 16384;
    float4 s = Mp4[e4];
    #pragma unroll
    for (int c = 1; c < 16; ++c) {
        float4 t = Mp4[(size_t)c * 1024 + e4];
        s.x += t.x; s.y += t.y; s.z += t.z; s.w += t.w;
    }
    s.x *= ATT_SCALE; s.y *= ATT_SCALE; s.z *= ATT_SCALE; s.w *= ATT_SCALE;
    ((float4*)Mred)[(size_t)p * 1024 + e4] = s;
}

// ---------------------------------------------------------------------------
// Phase B: register-tiled T = Q@Mred + fused softmax (64x64 tile, one barrier).
// MH written as fp16.
// ---------------------------------------------------------------------------
__global__ __launch_bounds__(256, 2) void attn_gemm(
    const float* __restrict__ Qbuf, const float* __restrict__ Mred,
    u16* __restrict__ MH)
{
    const int chunk = blockIdx.x;
    const int p     = blockIdx.y;
    const int b = p / NHEAD, h = p % NHEAD;
    const float* Qb = Qbuf + (size_t)b * PER_BATCH + (size_t)h * PER_HEAD + (size_t)chunk * 64 * DKH;
    u16* MHb        = MH   + (size_t)b * PER_BATCH + (size_t)h * PER_HEAD + (size_t)chunk * 64 * DKH;

    __shared__ float QsT[64][65];
    __shared__ __align__(16) float SM[64][64];

    const int tid = threadIdx.x;

    const float4* M4 = (const float4*)(Mred + (size_t)p * 4096);
    float4* SM4 = (float4*)SM;
    #pragma unroll
    for (int r = 0; r < 4; ++r) {
        int e4 = tid + 256 * r;
        SM4[e4] = M4[e4];
        int row = e4 >> 4, c4 = e4 & 15;
        float4 v = *(const float4*)&Qb[(size_t)row * DKH + c4 * 4];
        QsT[c4 * 4 + 0][row] = v.x; QsT[c4 * 4 + 1][row] = v.y;
        QsT[c4 * 4 + 2][row] = v.z; QsT[c4 * 4 + 3][row] = v.w;
    }
    __syncthreads();

    const int tx = tid & 15;
    const int ty = tid >> 4;

    float acc[4][4];
    #pragma unroll
    for (int i = 0; i < 4; ++i)
        #pragma unroll
        for (int j = 0; j < 4; ++j) acc[i][j] = 0.f;

    #pragma unroll 4
    for (int k = 0; k < 64; ++k) {
        float4 bv = *(const float4*)&SM[k][tx * 4];
        float aa[4] = {QsT[k][ty * 4 + 0], QsT[k][ty * 4 + 1],
                       QsT[k][ty * 4 + 2], QsT[k][ty * 4 + 3]};
        float bb[4] = {bv.x, bv.y, bv.z, bv.w};
        #pragma unroll
        for (int i = 0; i < 4; ++i)
            #pragma unroll
            for (int j = 0; j < 4; ++j)
                acc[i][j] += aa[i] * bb[j];
    }

    #pragma unroll
    for (int i = 0; i < 4; ++i) {
        float m = fmaxf(fmaxf(acc[i][0], acc[i][1]), fmaxf(acc[i][2], acc[i][3]));
        #pragma unroll
        for (int off = 1; off < 16; off <<= 1)
            m = fmaxf(m, __shfl_xor(m, off, 64));
        float e0 = __expf(acc[i][0] - m), e1 = __expf(acc[i][1] - m);
        float e2 = __expf(acc[i][2] - m), e3 = __expf(acc[i][3] - m);
        float s = (e0 + e1) + (e2 + e3);
        #pragma unroll
        for (int off = 1; off < 16; off <<= 1)
            s += __shfl_xor(s, off, 64);
        float inv = 1.f / s;
        u16 o0 = f2h(e0 * inv), o1 = f2h(e1 * inv);
        u16 o2 = f2h(e2 * inv), o3 = f2h(e3 * inv);
        uint2 pk; pk.x = (u32)o0 | ((u32)o1 << 16); pk.y = (u32)o2 | ((u32)o3 << 16);
        const int row = ty * 4 + i;
        *(uint2*)&MHb[(size_t)row * DKH + tx * 4] = pk;
    }
}

// ---------------------------------------------------------------------------
extern "C" void kernel_launch(void* const* d_in, const int* in_sizes, int n_in,
                              void* d_out, int out_size, void* d_ws, size_t ws_size,
                              hipStream_t stream)
{
    const float* x  = (const float*)d_in[0];
    const float* Wq = (const float*)d_in[1];
    const float* bq = (const float*)d_in[2];
    const float* Wk = (const float*)d_in[3];
    const float* bk = (const float*)d_in[4];
    const float* Wv = (const float*)d_in[5];
    const float* bv = (const float*)d_in[6];
    const float* Wo = (const float*)d_in[7];
    const float* bo = (const float*)d_in[8];
    const float* Wf = (const float*)d_in[9];
    const float* bf = (const float*)d_in[10];
    float* out = (float*)d_out;

    // Workspace (floats): Q(3.1M) K(3.1M) V(3.1M) Mpart(1.57M) Mred(98K) bc(768)
    // then u16 (fp16): xh(3.1M) Wh3(1.77M) Wfh(0.59M) WoT(0.59M) Wcb(0.59M)
    // alias: MH -> xh (dead after qkv_gemm).
    float* ws_f = (float*)d_ws;
    float* Q   = ws_f;
    float* Kb  = ws_f + 3145728;
    float* Vb  = ws_f + 6291456;
    float* Mp  = ws_f + 9437184;
    float* Mrd = ws_f + 11010048;
    float* bc  = ws_f + 11108352;
    u16* ub  = (u16*)(ws_f + 11109376);
    u16* xh  = ub;
    u16* Wh3 = ub + 3145728;
    u16* Wfh = Wh3 + 1769472;
    u16* WoT = Wfh + 589824;
    u16* Wcb = WoT + 589824;
    u16* MH  = xh;

    dim3 blk(256);
    // All casts + Wo transpose + bc in one launch
    conv_all<<<dim3(576, 7), blk, 0, stream>>>(x, Wq, Wk, Wv, Wf, Wo, bo, bf,
                                               xh, Wh3, Wfh, WoT, bc);
    // QKV: fp16 single-pass MFMA GEMM, 128x128 tiles
    qkv_gemm<<<dim3(32, 18), blk, 0, stream>>>(xh, Wh3, bq, bk, bv, Q, Kb, Vb);
    // Attention core (fp32)
    kv_outer<<<dim3(16, 24), blk, 0, stream>>>(Kb, Vb, Mp);
    reduce_M<<<dim3(24, 4), blk, 0, stream>>>(Mp, Mrd);
    // Wc = Wf @ Wo (fp16 MFMA, fp16 out)
    gemm_f16<<<dim3(12, 6), blk, 0, stream>>>(Wfh, WoT, nullptr, Wcb, 1);
    // Softmax rows -> MH (fp16)
    attn_gemm<<<dim3(32, 24), blk, 0, stream>>>(Q, Mrd, MH);
    // Fused output projection: out = MH @ Wc^T + bc (fp32 out)
    gemm_f16<<<dim3(64, 6), blk, 0, stream>>>(MH, Wcb, bc, out, 0);
}